// Round 4
// baseline (344.718 us; speedup 1.0000x reference)
//
#include <hip/hip_runtime.h>
#include <math.h>

// Problem constants (from reference): B=2, S=2048, D=1024, H=16, DH=64
#define BATCH 2
#define SEQ 2048
#define DMODEL 1024
#define NHEAD 16
#define DHEAD 64
#define QKV_COLS (3 * DMODEL)          // 3072
#define EPS 1e-8f

typedef short bf16x8 __attribute__((ext_vector_type(8)));   // 8 bf16 (4 VGPRs)
typedef float f32x4 __attribute__((ext_vector_type(4)));    // 4 fp32 acc

// round-to-nearest-even float -> bf16 (as raw ushort)
static __device__ __forceinline__ unsigned short f2bf(float x) {
  unsigned u = __float_as_uint(x);
  u += 0x7fffu + ((u >> 16) & 1u);
  return (unsigned short)(u >> 16);
}

// async global->LDS, 16 B per lane (global_load_lds_dwordx4).
static __device__ __forceinline__ void async_ld16(const unsigned short* g,
                                                  unsigned short* l) {
  __builtin_amdgcn_global_load_lds(
      (const __attribute__((address_space(1))) void*)g,
      (__attribute__((address_space(3))) void*)(unsigned int)(unsigned long long)l,
      16, 0, 0);
}

// ---------------------------------------------------------------------------
// Prep 1: x f32 [M][K] -> bf16 same layout. 4 floats/thread.
// ---------------------------------------------------------------------------
__global__ __launch_bounds__(256) void convert_x_kernel(
    const float* __restrict__ x, unsigned short* __restrict__ xb) {
  const size_t i = ((size_t)blockIdx.x * 256 + threadIdx.x) * 4;
  const float4 a = *(const float4*)(x + i);
  ushort4 r;
  r.x = f2bf(a.x); r.y = f2bf(a.y); r.z = f2bf(a.z); r.w = f2bf(a.w);
  *(ushort4*)(xb + i) = r;
}

// ---------------------------------------------------------------------------
// Prep 2: W f32 [K][N] -> Wt bf16 [N][K] (transposed), 32x32 LDS tiles.
// ---------------------------------------------------------------------------
__global__ __launch_bounds__(256) void transpose_w_kernel(
    const float* __restrict__ W, unsigned short* __restrict__ Wt, int K, int N) {
  __shared__ float tile[32][33];
  const int n0 = blockIdx.x * 32;
  const int k0 = blockIdx.y * 32;
  const int tx = threadIdx.x, ty = threadIdx.y;
#pragma unroll
  for (int i = 0; i < 4; ++i)
    tile[ty + i * 8][tx] = W[(size_t)(k0 + ty + i * 8) * N + n0 + tx];
  __syncthreads();
#pragma unroll
  for (int i = 0; i < 4; ++i)
    Wt[(size_t)(n0 + ty + i * 8) * K + k0 + tx] = f2bf(tile[tx][ty + i * 8]);
}

// ---------------------------------------------------------------------------
// bf16 MFMA GEMM (m97-style): C[M,N] f32 = A[M,K]bf16 @ Bt[N,K]bf16^T.
// ---------------------------------------------------------------------------
__global__ __launch_bounds__(256) void sgemm_bf16_kernel(
    const unsigned short* __restrict__ A, const unsigned short* __restrict__ Bt,
    float* __restrict__ C, int M, int N, int K) {
  __shared__ unsigned short As[128 * 32];   // [m][k] tile, row-major
  __shared__ unsigned short Bs[128 * 32];   // [n][k] tile, row-major

  const int t = threadIdx.x;
  const int w = t >> 6;
  const int lane = t & 63;
  const int quad = lane >> 4;
  const int lr = lane & 15;
  const int wr = w >> 1, wc = w & 1;
  const int m0 = blockIdx.y * 128;
  const int n0 = blockIdx.x * 128;

  const int srow = w * 32 + (lane >> 2);
  const int scol = (lane & 3) * 8;
  const unsigned short* ga = A + (size_t)(m0 + srow) * K + scol;
  const unsigned short* gb = Bt + (size_t)(n0 + srow) * K + scol;
  unsigned short* la = &As[(w * 32) * 32];
  unsigned short* lb = &Bs[(w * 32) * 32];

  f32x4 acc[4][4];
  const f32x4 zero4 = {0.f, 0.f, 0.f, 0.f};
#pragma unroll
  for (int i = 0; i < 4; ++i)
#pragma unroll
    for (int j = 0; j < 4; ++j) acc[i][j] = zero4;

  for (int k0 = 0; k0 < K; k0 += 32) {
#pragma unroll
    for (int i = 0; i < 2; ++i) {
      async_ld16(ga + (size_t)(i * 16) * K + k0, la + i * 16 * 32);
      async_ld16(gb + (size_t)(i * 16) * K + k0, lb + i * 16 * 32);
    }
    __syncthreads();

    bf16x8 af[4], bf[4];
#pragma unroll
    for (int i = 0; i < 4; ++i)
      af[i] = *(const bf16x8*)&As[(wr * 64 + i * 16 + lr) * 32 + quad * 8];
#pragma unroll
    for (int j = 0; j < 4; ++j)
      bf[j] = *(const bf16x8*)&Bs[(wc * 64 + j * 16 + lr) * 32 + quad * 8];
#pragma unroll
    for (int i = 0; i < 4; ++i)
#pragma unroll
      for (int j = 0; j < 4; ++j)
        acc[i][j] = __builtin_amdgcn_mfma_f32_16x16x32_bf16(af[i], bf[j], acc[i][j], 0, 0, 0);
    __syncthreads();
  }

#pragma unroll
  for (int i = 0; i < 4; ++i)
#pragma unroll
    for (int r = 0; r < 4; ++r) {
      float* c = C + (size_t)(m0 + wr * 64 + i * 16 + quad * 4 + r) * N + n0 + wc * 64 + lr;
#pragma unroll
      for (int j = 0; j < 4; ++j) c[j * 16] = acc[i][j][r];
    }
}

// ---------------------------------------------------------------------------
// qknorm: read qkv f32 [B,S,3D]; L2-normalize q,k per head (fold tau/sqrt(DH)
// into q); emit bf16 Q/K/V head-major [B,H,S,DH].
// ---------------------------------------------------------------------------
__global__ __launch_bounds__(256) void qknorm_kernel(
    const float* __restrict__ qkv, const float* __restrict__ tau,
    unsigned short* __restrict__ Qh, unsigned short* __restrict__ Kh,
    unsigned short* __restrict__ Vh) {
  const int lane = threadIdx.x & 63;
  const int widx = blockIdx.y * 4 + (threadIdx.x >> 6);  // 0..47
  const int which = widx >> 4;                           // 0=q, 1=k, 2=v
  const int h = widx & 15;
  const int bs = blockIdx.x;
  const int b = bs >> 11;
  const int s = bs & 2047;

  const float v = qkv[(size_t)bs * QKV_COLS + which * DMODEL + h * DHEAD + lane];
  float out;
  if (which == 2) {
    out = v;
  } else {
    float ss = v * v;
#pragma unroll
    for (int off = 32; off > 0; off >>= 1) ss += __shfl_xor(ss, off, 64);
    float scale = 1.0f / (sqrtf(ss) + EPS);
    if (which == 0) scale *= tau[h] * 0.125f;  // tau / sqrt(DHEAD)
    out = v * scale;
  }
  unsigned short* dst = (which == 0) ? Qh : (which == 1) ? Kh : Vh;
  dst[((size_t)(b * NHEAD + h) * SEQ + s) * DHEAD + lane] = f2bf(out);
}

// ---------------------------------------------------------------------------
// V transpose: Vh [BH][S][DH] -> Vt [BH][DH][S]. 64x64 LDS tiles.
// ---------------------------------------------------------------------------
__global__ __launch_bounds__(256) void vtrans_kernel(
    const unsigned short* __restrict__ Vh, unsigned short* __restrict__ Vt) {
  __shared__ unsigned short tile[64][72];
  const int bh = blockIdx.x;
  const int s0 = blockIdx.y * 64;
  const int t = threadIdx.x;
  const int sr = t >> 2;          // 0..63
  const int dc = (t & 3) * 16;    // 0,16,32,48
  const unsigned short* src = Vh + ((size_t)bh * SEQ + s0 + sr) * DHEAD + dc;
  *(bf16x8*)&tile[sr][dc]     = *(const bf16x8*)(src);
  *(bf16x8*)&tile[sr][dc + 8] = *(const bf16x8*)(src + 8);
  __syncthreads();
  const int dr = t >> 2;          // 0..63 (d row)
  const int sc = (t & 3) * 16;    // s chunk
  unsigned short buf[16];
#pragma unroll
  for (int i = 0; i < 16; ++i) buf[i] = tile[sc + i][dr];
  unsigned short* dst = Vt + ((size_t)bh * DHEAD + dr) * SEQ + s0 + sc;
  *(bf16x8*)dst       = *(const bf16x8*)buf;
  *(bf16x8*)(dst + 8) = *(const bf16x8*)(buf + 8);
}

// ---------------------------------------------------------------------------
// Causal flash attention, bf16 MFMA, barrier-free.
// grid = 512 blocks (bh = idx&31, qblk = 15 - idx>>5, descending work),
// 4 waves/block; wave w owns q-tiles {qblk*128+w*16, +64} (16 rows each).
// 64-key steps: 16 QK MFMAs + fixed-max softmax (|logit| <= tau/8, no online
// max/rescale) + per-wave P LDS round-trip + 16 PV MFMAs (V^T direct from
// global [BH][DH][S]). l reduced once at epilogue. No __syncthreads.
// ---------------------------------------------------------------------------
#define PL_STRIDE 72   // shorts; 144B rows -> uniform bank spread for b128

__global__ __launch_bounds__(256) void attn_kernel(
    const unsigned short* __restrict__ Qh, const unsigned short* __restrict__ Kh,
    const unsigned short* __restrict__ Vt, const float* __restrict__ tau,
    unsigned short* __restrict__ attnb) {
  __shared__ unsigned short Pl[4][32 * PL_STRIDE];   // per-wave P: [q 0..31][key 0..63]

  const int idx = blockIdx.x;
  const int qblk = (SEQ / 128 - 1) - (idx >> 5);   // heaviest blocks first
  const int bh = idx & 31;
  const int b = bh >> 4;
  const int h = bh & 15;
  const int t = threadIdx.x;
  const int w = t >> 6;
  const int lane = t & 63;
  const int quad = lane >> 4;
  const int lr = lane & 15;

  const float mh = tau[h] * 0.125f;   // fixed softmax max: |logit| <= tau/8

  const unsigned short* Qp = Qh + (size_t)bh * SEQ * DHEAD;
  const unsigned short* Kp = Kh + (size_t)bh * SEQ * DHEAD;
  const unsigned short* Vp = Vt + (size_t)bh * DHEAD * SEQ;
  unsigned short* Pw = &Pl[w][0];

  const int qb[2] = {qblk * 128 + w * 16, qblk * 128 + w * 16 + 64};

  bf16x8 aq[2][2];
#pragma unroll
  for (int qt = 0; qt < 2; ++qt) {
    aq[qt][0] = *(const bf16x8*)(Qp + (size_t)(qb[qt] + lr) * DHEAD + quad * 8);
    aq[qt][1] = *(const bf16x8*)(Qp + (size_t)(qb[qt] + lr) * DHEAD + 32 + quad * 8);
  }

  const f32x4 zero4 = {0.f, 0.f, 0.f, 0.f};
  f32x4 o[2][4];
#pragma unroll
  for (int qt = 0; qt < 2; ++qt)
#pragma unroll
    for (int nt = 0; nt < 4; ++nt) o[qt][nt] = zero4;
  float l_[2][4] = {{0.f, 0.f, 0.f, 0.f}, {0.f, 0.f, 0.f, 0.f}};

  const int kend = qblk * 128 + 128;
  for (int k0 = 0; k0 < kend; k0 += 64) {
#pragma unroll
    for (int qt = 0; qt < 2; ++qt) {
      if (k0 <= qb[qt] + 15) {              // wave-uniform: tile has live keys
        const bool anymask = (k0 + 63 > qb[qt]);
        f32x4 c[4];
#pragma unroll
        for (int kt = 0; kt < 4; ++kt) {
          const unsigned short* kr = Kp + (size_t)(k0 + kt * 16 + lr) * DHEAD;
          const bf16x8 b0 = *(const bf16x8*)(kr + quad * 8);
          const bf16x8 b1 = *(const bf16x8*)(kr + 32 + quad * 8);
          f32x4 cc = __builtin_amdgcn_mfma_f32_16x16x32_bf16(aq[qt][0], b0, zero4, 0, 0, 0);
          c[kt] = __builtin_amdgcn_mfma_f32_16x16x32_bf16(aq[qt][1], b1, cc, 0, 0, 0);
        }
#pragma unroll
        for (int r = 0; r < 4; ++r) {
          const int qrow = qb[qt] + quad * 4 + r;
          float ps = 0.f;
#pragma unroll
          for (int kt = 0; kt < 4; ++kt) {
            const int key = k0 + kt * 16 + lr;
            float p = __expf(c[kt][r] - mh);
            if (anymask) p = (key <= qrow) ? p : 0.f;
            ps += p;
            Pw[(qt * 16 + quad * 4 + r) * PL_STRIDE + kt * 16 + lr] = f2bf(p);
          }
          l_[qt][r] += ps;
        }
      }
    }

    // PV: pa from LDS (A layout), vb direct from global V^T; share vb across qt.
    const bool do0 = (k0 <= qb[0] + 15);
    bf16x8 pa[2][2];
#pragma unroll
    for (int c2 = 0; c2 < 2; ++c2) {
      if (do0) pa[0][c2] = *(const bf16x8*)&Pw[lr * PL_STRIDE + c2 * 32 + quad * 8];
      pa[1][c2] = *(const bf16x8*)&Pw[(16 + lr) * PL_STRIDE + c2 * 32 + quad * 8];
    }
#pragma unroll
    for (int c2 = 0; c2 < 2; ++c2)
#pragma unroll
      for (int nt = 0; nt < 4; ++nt) {
        const bf16x8 vb = *(const bf16x8*)(Vp + (size_t)(nt * 16 + lr) * SEQ + k0 + c2 * 32 + quad * 8);
        if (do0) o[0][nt] = __builtin_amdgcn_mfma_f32_16x16x32_bf16(pa[0][c2], vb, o[0][nt], 0, 0, 0);
        o[1][nt] = __builtin_amdgcn_mfma_f32_16x16x32_bf16(pa[1][c2], vb, o[1][nt], 0, 0, 0);
      }
  }

  // epilogue: reduce l across the 16-lane row group once, normalize, write bf16
#pragma unroll
  for (int qt = 0; qt < 2; ++qt)
#pragma unroll
    for (int r = 0; r < 4; ++r) {
      float lv = l_[qt][r];
      lv += __shfl_xor(lv, 1, 16);
      lv += __shfl_xor(lv, 2, 16);
      lv += __shfl_xor(lv, 4, 16);
      lv += __shfl_xor(lv, 8, 16);
      const float inv = 1.0f / lv;
      const int qrow = qb[qt] + quad * 4 + r;
      unsigned short* ar = attnb + ((size_t)(b * SEQ + qrow)) * DMODEL + h * DHEAD;
#pragma unroll
      for (int nt = 0; nt < 4; ++nt) ar[nt * 16 + lr] = f2bf(o[qt][nt][r] * inv);
    }
}

// ---------------------------------------------------------------------------
// Launch
// ---------------------------------------------------------------------------
extern "C" void kernel_launch(void* const* d_in, const int* in_sizes, int n_in,
                              void* d_out, int out_size, void* d_ws, size_t ws_size,
                              hipStream_t stream) {
  const float* x    = (const float*)d_in[0];
  // d_in[1]: fixed causal tril mask -> handled analytically, never read.
  const float* Wqkv = (const float*)d_in[2];
  const float* Wo   = (const float*)d_in[3];
  const float* tau  = (const float*)d_in[4];
  float* out = (float*)d_out;

  // workspace layout (92.3 MB, unchanged footprint; aliases reuse dead bufs):
  float* qkv = (float*)d_ws;                                    // [B,S,3D] f32
  unsigned short* attnb = (unsigned short*)d_ws;                // aliases dead qkv
  unsigned short* Qh = (unsigned short*)(qkv + (size_t)BATCH * SEQ * QKV_COLS);
  unsigned short* Kh = Qh + (size_t)BATCH * NHEAD * SEQ * DHEAD;
  unsigned short* Vh = Kh + (size_t)BATCH * NHEAD * SEQ * DHEAD;
  unsigned short* Xb = Vh + (size_t)BATCH * NHEAD * SEQ * DHEAD;      // bf16 [B*S][D]
  unsigned short* Vt = Xb;                                            // aliases dead Xb (8.4 MB each)
  unsigned short* Wqkv_t = Xb + (size_t)BATCH * SEQ * DMODEL;         // bf16 [3D][D]
  unsigned short* Wo_t = Wqkv_t + (size_t)DMODEL * QKV_COLS;          // bf16 [D][D]

  const int M = BATCH * SEQ;  // 4096

  // 0) prep: bf16 conversions + weight transposes
  convert_x_kernel<<<(M * DMODEL) / (256 * 4), 256, 0, stream>>>(x, Xb);
  transpose_w_kernel<<<dim3(QKV_COLS / 32, DMODEL / 32), dim3(32, 8), 0, stream>>>(
      Wqkv, Wqkv_t, DMODEL, QKV_COLS);
  transpose_w_kernel<<<dim3(DMODEL / 32, DMODEL / 32), dim3(32, 8), 0, stream>>>(
      Wo, Wo_t, DMODEL, DMODEL);

  // 1) qkv = x @ Wqkv   (M=4096, N=3072, K=1024), f32 out
  sgemm_bf16_kernel<<<dim3(QKV_COLS / 128, M / 128), 256, 0, stream>>>(
      Xb, Wqkv_t, qkv, M, QKV_COLS, DMODEL);

  // 2) qk-norm -> bf16 head-major Q/K/V
  qknorm_kernel<<<dim3(BATCH * SEQ, 12), 256, 0, stream>>>(qkv, tau, Qh, Kh, Vh);

  // 3) V -> V^T [BH][DH][S]   (Xb is dead after GEMM1)
  vtrans_kernel<<<dim3(BATCH * NHEAD, SEQ / 64), 256, 0, stream>>>(Vh, Vt);

  // 4) causal MFMA flash attention -> attnb bf16 [B,S,D] (aliases dead qkv)
  attn_kernel<<<dim3(BATCH * NHEAD * SEQ / 128), 256, 0, stream>>>(
      Qh, Kh, Vt, tau, attnb);

  // 5) out = attn @ Wo  (M=4096, N=1024, K=1024), f32 out
  sgemm_bf16_kernel<<<dim3(DMODEL / 128, M / 128), 256, 0, stream>>>(
      attnb, Wo_t, out, M, DMODEL, DMODEL);
}

// Round 5
// 327.500 us; speedup vs baseline: 1.0526x; 1.0526x over previous
//
#include <hip/hip_runtime.h>
#include <math.h>

// Problem constants (from reference): B=2, S=2048, D=1024, H=16, DH=64
#define BATCH 2
#define SEQ 2048
#define DMODEL 1024
#define NHEAD 16
#define DHEAD 64
#define QKV_COLS (3 * DMODEL)          // 3072
#define EPS 1e-8f

typedef short bf16x8 __attribute__((ext_vector_type(8)));   // 8 bf16 (4 VGPRs)
typedef float f32x4 __attribute__((ext_vector_type(4)));    // 4 fp32 acc

// round-to-nearest-even float -> bf16 (as raw ushort)
static __device__ __forceinline__ unsigned short f2bf(float x) {
  unsigned u = __float_as_uint(x);
  u += 0x7fffu + ((u >> 16) & 1u);
  return (unsigned short)(u >> 16);
}

// async global->LDS, 16 B per lane (global_load_lds_dwordx4).
static __device__ __forceinline__ void async_ld16(const unsigned short* g,
                                                  unsigned short* l) {
  __builtin_amdgcn_global_load_lds(
      (const __attribute__((address_space(1))) void*)g,
      (__attribute__((address_space(3))) void*)(unsigned int)(unsigned long long)l,
      16, 0, 0);
}

// ---------------------------------------------------------------------------
// Prep 1: x f32 [M][K] -> bf16 same layout. 4 floats/thread.
// ---------------------------------------------------------------------------
__global__ __launch_bounds__(256) void convert_x_kernel(
    const float* __restrict__ x, unsigned short* __restrict__ xb) {
  const size_t i = ((size_t)blockIdx.x * 256 + threadIdx.x) * 4;
  const float4 a = *(const float4*)(x + i);
  ushort4 r;
  r.x = f2bf(a.x); r.y = f2bf(a.y); r.z = f2bf(a.z); r.w = f2bf(a.w);
  *(ushort4*)(xb + i) = r;
}

// ---------------------------------------------------------------------------
// Prep 2: W f32 [K][N] -> Wt bf16 [N][K] (transposed), 32x32 LDS tiles.
// ---------------------------------------------------------------------------
__global__ __launch_bounds__(256) void transpose_w_kernel(
    const float* __restrict__ W, unsigned short* __restrict__ Wt, int K, int N) {
  __shared__ float tile[32][33];
  const int n0 = blockIdx.x * 32;
  const int k0 = blockIdx.y * 32;
  const int tx = threadIdx.x, ty = threadIdx.y;
#pragma unroll
  for (int i = 0; i < 4; ++i)
    tile[ty + i * 8][tx] = W[(size_t)(k0 + ty + i * 8) * N + n0 + tx];
  __syncthreads();
#pragma unroll
  for (int i = 0; i < 4; ++i)
    Wt[(size_t)(n0 + ty + i * 8) * K + k0 + tx] = f2bf(tile[tx][ty + i * 8]);
}

// ---------------------------------------------------------------------------
// bf16 MFMA GEMM (m97-style): C[M,N] f32 = A[M,K]bf16 @ Bt[N,K]bf16^T.
// ---------------------------------------------------------------------------
__global__ __launch_bounds__(256) void sgemm_bf16_kernel(
    const unsigned short* __restrict__ A, const unsigned short* __restrict__ Bt,
    float* __restrict__ C, int M, int N, int K) {
  __shared__ unsigned short As[128 * 32];   // [m][k] tile, row-major
  __shared__ unsigned short Bs[128 * 32];   // [n][k] tile, row-major

  const int t = threadIdx.x;
  const int w = t >> 6;
  const int lane = t & 63;
  const int quad = lane >> 4;
  const int lr = lane & 15;
  const int wr = w >> 1, wc = w & 1;
  const int m0 = blockIdx.y * 128;
  const int n0 = blockIdx.x * 128;

  const int srow = w * 32 + (lane >> 2);
  const int scol = (lane & 3) * 8;
  const unsigned short* ga = A + (size_t)(m0 + srow) * K + scol;
  const unsigned short* gb = Bt + (size_t)(n0 + srow) * K + scol;
  unsigned short* la = &As[(w * 32) * 32];
  unsigned short* lb = &Bs[(w * 32) * 32];

  f32x4 acc[4][4];
  const f32x4 zero4 = {0.f, 0.f, 0.f, 0.f};
#pragma unroll
  for (int i = 0; i < 4; ++i)
#pragma unroll
    for (int j = 0; j < 4; ++j) acc[i][j] = zero4;

  for (int k0 = 0; k0 < K; k0 += 32) {
#pragma unroll
    for (int i = 0; i < 2; ++i) {
      async_ld16(ga + (size_t)(i * 16) * K + k0, la + i * 16 * 32);
      async_ld16(gb + (size_t)(i * 16) * K + k0, lb + i * 16 * 32);
    }
    __syncthreads();

    bf16x8 af[4], bf[4];
#pragma unroll
    for (int i = 0; i < 4; ++i)
      af[i] = *(const bf16x8*)&As[(wr * 64 + i * 16 + lr) * 32 + quad * 8];
#pragma unroll
    for (int j = 0; j < 4; ++j)
      bf[j] = *(const bf16x8*)&Bs[(wc * 64 + j * 16 + lr) * 32 + quad * 8];
#pragma unroll
    for (int i = 0; i < 4; ++i)
#pragma unroll
      for (int j = 0; j < 4; ++j)
        acc[i][j] = __builtin_amdgcn_mfma_f32_16x16x32_bf16(af[i], bf[j], acc[i][j], 0, 0, 0);
    __syncthreads();
  }

#pragma unroll
  for (int i = 0; i < 4; ++i)
#pragma unroll
    for (int r = 0; r < 4; ++r) {
      float* c = C + (size_t)(m0 + wr * 64 + i * 16 + quad * 4 + r) * N + n0 + wc * 64 + lr;
#pragma unroll
      for (int j = 0; j < 4; ++j) c[j * 16] = acc[i][j][r];
    }
}

// ---------------------------------------------------------------------------
// qknorm: read qkv f32 [B,S,3D]; L2-normalize q,k per head (fold tau/sqrt(DH)
// into q); emit bf16 Q/K/V head-major [B,H,S,DH].
// ---------------------------------------------------------------------------
__global__ __launch_bounds__(256) void qknorm_kernel(
    const float* __restrict__ qkv, const float* __restrict__ tau,
    unsigned short* __restrict__ Qh, unsigned short* __restrict__ Kh,
    unsigned short* __restrict__ Vh) {
  const int lane = threadIdx.x & 63;
  const int widx = blockIdx.y * 4 + (threadIdx.x >> 6);  // 0..47
  const int which = widx >> 4;                           // 0=q, 1=k, 2=v
  const int h = widx & 15;
  const int bs = blockIdx.x;
  const int b = bs >> 11;
  const int s = bs & 2047;

  const float v = qkv[(size_t)bs * QKV_COLS + which * DMODEL + h * DHEAD + lane];
  float out;
  if (which == 2) {
    out = v;
  } else {
    float ss = v * v;
#pragma unroll
    for (int off = 32; off > 0; off >>= 1) ss += __shfl_xor(ss, off, 64);
    float scale = 1.0f / (sqrtf(ss) + EPS);
    if (which == 0) scale *= tau[h] * 0.125f;  // tau / sqrt(DHEAD)
    out = v * scale;
  }
  unsigned short* dst = (which == 0) ? Qh : (which == 1) ? Kh : Vh;
  dst[((size_t)(b * NHEAD + h) * SEQ + s) * DHEAD + lane] = f2bf(out);
}

// ---------------------------------------------------------------------------
// V transpose: Vh [BH][S][DH] -> Vt [BH][DH][S]. 64x64 LDS tiles.
// ---------------------------------------------------------------------------
__global__ __launch_bounds__(256) void vtrans_kernel(
    const unsigned short* __restrict__ Vh, unsigned short* __restrict__ Vt) {
  __shared__ unsigned short tile[64][72];
  const int bh = blockIdx.x;
  const int s0 = blockIdx.y * 64;
  const int t = threadIdx.x;
  const int sr = t >> 2;          // 0..63
  const int dc = (t & 3) * 16;    // 0,16,32,48
  const unsigned short* src = Vh + ((size_t)bh * SEQ + s0 + sr) * DHEAD + dc;
  *(bf16x8*)&tile[sr][dc]     = *(const bf16x8*)(src);
  *(bf16x8*)&tile[sr][dc + 8] = *(const bf16x8*)(src + 8);
  __syncthreads();
  const int dr = t >> 2;          // 0..63 (d row)
  const int sc = (t & 3) * 16;    // s chunk
  unsigned short buf[16];
#pragma unroll
  for (int i = 0; i < 16; ++i) buf[i] = tile[sc + i][dr];
  unsigned short* dst = Vt + ((size_t)bh * DHEAD + dr) * SEQ + s0 + sc;
  *(bf16x8*)dst       = *(const bf16x8*)buf;
  *(bf16x8*)(dst + 8) = *(const bf16x8*)(buf + 8);
}

// ---------------------------------------------------------------------------
// Causal flash attention, bf16 MFMA, barrier-free, software-pipelined.
// grid = 1024 blocks: bh = idx&31, qc = 31 - idx>>5 (descending work).
// 4 waves/block; wave w owns 16 q-rows starting at qc*64 + w*16.
// All waves run exactly qc+1 steps of 64 keys. Per step: 8 QK MFMAs
// (K from register double-buffer, prefetched one step ahead), fixed-max
// softmax (|logit| <= tau/8: no online max/rescale; l summed per-lane,
// reduced once at epilogue), per-wave P LDS round-trip (C->A layout),
// 8 PV MFMAs (V^T fragments loaded at step top from global [BH][DH][S]).
// Mask applies only on the provably-final step. No __syncthreads.
// ---------------------------------------------------------------------------
#define PL_STRIDE 72   // shorts; 144B rows -> uniform bank spread for b128

__global__ __launch_bounds__(256) void attn_kernel(
    const unsigned short* __restrict__ Qh, const unsigned short* __restrict__ Kh,
    const unsigned short* __restrict__ Vt, const float* __restrict__ tau,
    unsigned short* __restrict__ attnb) {
  __shared__ unsigned short Pl[4][16 * PL_STRIDE];   // per-wave P: [q 0..15][key 0..63]

  const int idx = blockIdx.x;
  const int qc = (SEQ / 64 - 1) - (idx >> 5);   // 31..0, heaviest first
  const int bh = idx & 31;
  const int b = bh >> 4;
  const int h = bh & 15;
  const int t = threadIdx.x;
  const int w = t >> 6;
  const int lane = t & 63;
  const int quad = lane >> 4;
  const int lr = lane & 15;

  const float mh = tau[h] * 0.125f;   // fixed softmax max: |logit| <= tau/8

  const unsigned short* Qp = Qh + (size_t)bh * SEQ * DHEAD;
  const unsigned short* Kp = Kh + (size_t)bh * SEQ * DHEAD;
  const unsigned short* Vp = Vt + (size_t)bh * DHEAD * SEQ;
  unsigned short* Pw = &Pl[w][0];

  const int qb = qc * 64 + w * 16;    // this wave's first q row

  const bf16x8 aq0 = *(const bf16x8*)(Qp + (size_t)(qb + lr) * DHEAD + quad * 8);
  const bf16x8 aq1 = *(const bf16x8*)(Qp + (size_t)(qb + lr) * DHEAD + 32 + quad * 8);

  const f32x4 zero4 = {0.f, 0.f, 0.f, 0.f};
  f32x4 o[4];
  o[0] = o[1] = o[2] = o[3] = zero4;
  float l_[4] = {0.f, 0.f, 0.f, 0.f};

  bf16x8 kbA[8], kbB[8];

  // K fragment loader: rows k0 + kt*16 + lr, two 32-d halves each.
#define LOADK(k0_, buf_)                                                        \
  do {                                                                          \
    _Pragma("unroll")                                                           \
    for (int kt = 0; kt < 4; ++kt) {                                            \
      const unsigned short* kr = Kp + (size_t)((k0_) + kt * 16 + lr) * DHEAD;   \
      (buf_)[kt * 2]     = *(const bf16x8*)(kr + quad * 8);                     \
      (buf_)[kt * 2 + 1] = *(const bf16x8*)(kr + 32 + quad * 8);                \
    }                                                                           \
  } while (0)

#define STEP(kb_, kn_, k0_, last_)                                              \
  do {                                                                          \
    /* V^T fragments for this step (used after softmax ~300cyc later) */        \
    bf16x8 vb[8];                                                               \
    _Pragma("unroll")                                                           \
    for (int nt = 0; nt < 4; ++nt)                                              \
      _Pragma("unroll")                                                         \
      for (int c2 = 0; c2 < 2; ++c2)                                            \
        vb[nt * 2 + c2] = *(const bf16x8*)(                                     \
            Vp + (size_t)(nt * 16 + lr) * SEQ + (k0_) + c2 * 32 + quad * 8);    \
    if (!(last_)) LOADK((k0_) + 64, kn_);  /* prefetch next K */                \
    f32x4 c[4];                                                                 \
    _Pragma("unroll")                                                           \
    for (int kt = 0; kt < 4; ++kt) {                                            \
      f32x4 cc = __builtin_amdgcn_mfma_f32_16x16x32_bf16(aq0, (kb_)[kt * 2], zero4, 0, 0, 0); \
      c[kt] = __builtin_amdgcn_mfma_f32_16x16x32_bf16(aq1, (kb_)[kt * 2 + 1], cc, 0, 0, 0);   \
    }                                                                           \
    _Pragma("unroll")                                                           \
    for (int r = 0; r < 4; ++r) {                                               \
      const int qrow = qb + quad * 4 + r;                                       \
      float ps = 0.f;                                                           \
      _Pragma("unroll")                                                         \
      for (int kt = 0; kt < 4; ++kt) {                                          \
        const int key = (k0_) + kt * 16 + lr;                                   \
        float p = __expf(c[kt][r] - mh);                                        \
        if (last_) p = (key <= qrow) ? p : 0.f;                                 \
        ps += p;                                                                \
        Pw[(quad * 4 + r) * PL_STRIDE + kt * 16 + lr] = f2bf(p);                \
      }                                                                         \
      l_[r] += ps;                                                              \
    }                                                                           \
    _Pragma("unroll")                                                           \
    for (int c2 = 0; c2 < 2; ++c2) {                                            \
      const bf16x8 pa = *(const bf16x8*)&Pw[lr * PL_STRIDE + c2 * 32 + quad * 8]; \
      _Pragma("unroll")                                                         \
      for (int nt = 0; nt < 4; ++nt)                                            \
        o[nt] = __builtin_amdgcn_mfma_f32_16x16x32_bf16(pa, vb[nt * 2 + c2], o[nt], 0, 0, 0); \
    }                                                                           \
  } while (0)

  LOADK(0, kbA);
  int k0 = 0;
  const int klast = qc * 64;
  while (true) {
    const bool lastA = (k0 == klast);
    STEP(kbA, kbB, k0, lastA);
    if (lastA) break;
    k0 += 64;
    const bool lastB = (k0 == klast);
    STEP(kbB, kbA, k0, lastB);
    if (lastB) break;
    k0 += 64;
  }
#undef STEP
#undef LOADK

  // epilogue: reduce l across the 16-lane col group once, normalize, write bf16
#pragma unroll
  for (int r = 0; r < 4; ++r) {
    float lv = l_[r];
    lv += __shfl_xor(lv, 1, 16);
    lv += __shfl_xor(lv, 2, 16);
    lv += __shfl_xor(lv, 4, 16);
    lv += __shfl_xor(lv, 8, 16);
    const float inv = 1.0f / lv;
    const int qrow = qb + quad * 4 + r;
    unsigned short* ar = attnb + ((size_t)(b * SEQ + qrow)) * DMODEL + h * DHEAD;
#pragma unroll
    for (int nt = 0; nt < 4; ++nt) ar[nt * 16 + lr] = f2bf(o[nt][r] * inv);
  }
}

// ---------------------------------------------------------------------------
// Launch
// ---------------------------------------------------------------------------
extern "C" void kernel_launch(void* const* d_in, const int* in_sizes, int n_in,
                              void* d_out, int out_size, void* d_ws, size_t ws_size,
                              hipStream_t stream) {
  const float* x    = (const float*)d_in[0];
  // d_in[1]: fixed causal tril mask -> handled analytically, never read.
  const float* Wqkv = (const float*)d_in[2];
  const float* Wo   = (const float*)d_in[3];
  const float* tau  = (const float*)d_in[4];
  float* out = (float*)d_out;

  // workspace layout (92.3 MB, unchanged footprint; aliases reuse dead bufs):
  float* qkv = (float*)d_ws;                                    // [B,S,3D] f32
  unsigned short* attnb = (unsigned short*)d_ws;                // aliases dead qkv
  unsigned short* Qh = (unsigned short*)(qkv + (size_t)BATCH * SEQ * QKV_COLS);
  unsigned short* Kh = Qh + (size_t)BATCH * NHEAD * SEQ * DHEAD;
  unsigned short* Vh = Kh + (size_t)BATCH * NHEAD * SEQ * DHEAD;
  unsigned short* Xb = Vh + (size_t)BATCH * NHEAD * SEQ * DHEAD;      // bf16 [B*S][D]
  unsigned short* Vt = Xb;                                            // aliases dead Xb
  unsigned short* Wqkv_t = Xb + (size_t)BATCH * SEQ * DMODEL;         // bf16 [3D][D]
  unsigned short* Wo_t = Wqkv_t + (size_t)DMODEL * QKV_COLS;          // bf16 [D][D]

  const int M = BATCH * SEQ;  // 4096

  // 0) prep: bf16 conversions + weight transposes
  convert_x_kernel<<<(M * DMODEL) / (256 * 4), 256, 0, stream>>>(x, Xb);
  transpose_w_kernel<<<dim3(QKV_COLS / 32, DMODEL / 32), dim3(32, 8), 0, stream>>>(
      Wqkv, Wqkv_t, DMODEL, QKV_COLS);
  transpose_w_kernel<<<dim3(DMODEL / 32, DMODEL / 32), dim3(32, 8), 0, stream>>>(
      Wo, Wo_t, DMODEL, DMODEL);

  // 1) qkv = x @ Wqkv   (M=4096, N=3072, K=1024), f32 out
  sgemm_bf16_kernel<<<dim3(QKV_COLS / 128, M / 128), 256, 0, stream>>>(
      Xb, Wqkv_t, qkv, M, QKV_COLS, DMODEL);

  // 2) qk-norm -> bf16 head-major Q/K/V
  qknorm_kernel<<<dim3(BATCH * SEQ, 12), 256, 0, stream>>>(qkv, tau, Qh, Kh, Vh);

  // 3) V -> V^T [BH][DH][S]   (Xb is dead after GEMM1)
  vtrans_kernel<<<dim3(BATCH * NHEAD, SEQ / 64), 256, 0, stream>>>(Vh, Vt);

  // 4) causal MFMA flash attention -> attnb bf16 [B,S,D] (aliases dead qkv)
  attn_kernel<<<dim3(BATCH * NHEAD * SEQ / 64), 256, 0, stream>>>(
      Qh, Kh, Vt, tau, attnb);

  // 5) out = attn @ Wo  (M=4096, N=1024, K=1024), f32 out
  sgemm_bf16_kernel<<<dim3(DMODEL / 128, M / 128), 256, 0, stream>>>(
      attnb, Wo_t, out, M, DMODEL, DMODEL);
}

// Round 6
// 322.256 us; speedup vs baseline: 1.0697x; 1.0163x over previous
//
#include <hip/hip_runtime.h>
#include <math.h>

// Problem constants (from reference): B=2, S=2048, D=1024, H=16, DH=64
#define BATCH 2
#define SEQ 2048
#define DMODEL 1024
#define NHEAD 16
#define DHEAD 64
#define QKV_COLS (3 * DMODEL)          // 3072
#define EPS 1e-8f
#define LOG2E 1.44269504f

typedef short bf16x8 __attribute__((ext_vector_type(8)));   // 8 bf16 (4 VGPRs)
typedef float f32x4 __attribute__((ext_vector_type(4)));    // 4 fp32 acc

// round-to-nearest-even float -> bf16 (as raw ushort)
static __device__ __forceinline__ unsigned short f2bf(float x) {
  unsigned u = __float_as_uint(x);
  u += 0x7fffu + ((u >> 16) & 1u);
  return (unsigned short)(u >> 16);
}

// async global->LDS, 16 B per lane (global_load_lds_dwordx4).
static __device__ __forceinline__ void async_ld16(const unsigned short* g,
                                                  unsigned short* l) {
  __builtin_amdgcn_global_load_lds(
      (const __attribute__((address_space(1))) void*)g,
      (__attribute__((address_space(3))) void*)(unsigned int)(unsigned long long)l,
      16, 0, 0);
}

// ---------------------------------------------------------------------------
// Prep 1: x f32 [M][K] -> bf16 same layout. 4 floats/thread.
// ---------------------------------------------------------------------------
__global__ __launch_bounds__(256) void convert_x_kernel(
    const float* __restrict__ x, unsigned short* __restrict__ xb) {
  const size_t i = ((size_t)blockIdx.x * 256 + threadIdx.x) * 4;
  const float4 a = *(const float4*)(x + i);
  ushort4 r;
  r.x = f2bf(a.x); r.y = f2bf(a.y); r.z = f2bf(a.z); r.w = f2bf(a.w);
  *(ushort4*)(xb + i) = r;
}

// ---------------------------------------------------------------------------
// Prep 2: W f32 [K][N] -> Wt bf16 [N][K] (transposed), 32x32 LDS tiles.
// ---------------------------------------------------------------------------
__global__ __launch_bounds__(256) void transpose_w_kernel(
    const float* __restrict__ W, unsigned short* __restrict__ Wt, int K, int N) {
  __shared__ float tile[32][33];
  const int n0 = blockIdx.x * 32;
  const int k0 = blockIdx.y * 32;
  const int tx = threadIdx.x, ty = threadIdx.y;
#pragma unroll
  for (int i = 0; i < 4; ++i)
    tile[ty + i * 8][tx] = W[(size_t)(k0 + ty + i * 8) * N + n0 + tx];
  __syncthreads();
#pragma unroll
  for (int i = 0; i < 4; ++i)
    Wt[(size_t)(n0 + ty + i * 8) * K + k0 + tx] = f2bf(tile[tx][ty + i * 8]);
}

// ---------------------------------------------------------------------------
// bf16 MFMA GEMM (m97-style): C[M,N] f32 = A[M,K]bf16 @ Bt[N,K]bf16^T.
// ---------------------------------------------------------------------------
__global__ __launch_bounds__(256) void sgemm_bf16_kernel(
    const unsigned short* __restrict__ A, const unsigned short* __restrict__ Bt,
    float* __restrict__ C, int M, int N, int K) {
  __shared__ unsigned short As[128 * 32];   // [m][k] tile, row-major
  __shared__ unsigned short Bs[128 * 32];   // [n][k] tile, row-major

  const int t = threadIdx.x;
  const int w = t >> 6;
  const int lane = t & 63;
  const int quad = lane >> 4;
  const int lr = lane & 15;
  const int wr = w >> 1, wc = w & 1;
  const int m0 = blockIdx.y * 128;
  const int n0 = blockIdx.x * 128;

  const int srow = w * 32 + (lane >> 2);
  const int scol = (lane & 3) * 8;
  const unsigned short* ga = A + (size_t)(m0 + srow) * K + scol;
  const unsigned short* gb = Bt + (size_t)(n0 + srow) * K + scol;
  unsigned short* la = &As[(w * 32) * 32];
  unsigned short* lb = &Bs[(w * 32) * 32];

  f32x4 acc[4][4];
  const f32x4 zero4 = {0.f, 0.f, 0.f, 0.f};
#pragma unroll
  for (int i = 0; i < 4; ++i)
#pragma unroll
    for (int j = 0; j < 4; ++j) acc[i][j] = zero4;

  for (int k0 = 0; k0 < K; k0 += 32) {
#pragma unroll
    for (int i = 0; i < 2; ++i) {
      async_ld16(ga + (size_t)(i * 16) * K + k0, la + i * 16 * 32);
      async_ld16(gb + (size_t)(i * 16) * K + k0, lb + i * 16 * 32);
    }
    __syncthreads();

    bf16x8 af[4], bf[4];
#pragma unroll
    for (int i = 0; i < 4; ++i)
      af[i] = *(const bf16x8*)&As[(wr * 64 + i * 16 + lr) * 32 + quad * 8];
#pragma unroll
    for (int j = 0; j < 4; ++j)
      bf[j] = *(const bf16x8*)&Bs[(wc * 64 + j * 16 + lr) * 32 + quad * 8];
#pragma unroll
    for (int i = 0; i < 4; ++i)
#pragma unroll
      for (int j = 0; j < 4; ++j)
        acc[i][j] = __builtin_amdgcn_mfma_f32_16x16x32_bf16(af[i], bf[j], acc[i][j], 0, 0, 0);
    __syncthreads();
  }

#pragma unroll
  for (int i = 0; i < 4; ++i)
#pragma unroll
    for (int r = 0; r < 4; ++r) {
      float* c = C + (size_t)(m0 + wr * 64 + i * 16 + quad * 4 + r) * N + n0 + wc * 64 + lr;
#pragma unroll
      for (int j = 0; j < 4; ++j) c[j * 16] = acc[i][j][r];
    }
}

// ---------------------------------------------------------------------------
// qknorm: read qkv f32 [B,S,3D]; L2-normalize q,k per head; fold
// tau/sqrt(DH) * log2(e) into q (so attention uses exp2); emit bf16 Q/K/V
// head-major [B,H,S,DH].
// ---------------------------------------------------------------------------
__global__ __launch_bounds__(256) void qknorm_kernel(
    const float* __restrict__ qkv, const float* __restrict__ tau,
    unsigned short* __restrict__ Qh, unsigned short* __restrict__ Kh,
    unsigned short* __restrict__ Vh) {
  const int lane = threadIdx.x & 63;
  const int widx = blockIdx.y * 4 + (threadIdx.x >> 6);  // 0..47
  const int which = widx >> 4;                           // 0=q, 1=k, 2=v
  const int h = widx & 15;
  const int bs = blockIdx.x;
  const int b = bs >> 11;
  const int s = bs & 2047;

  const float v = qkv[(size_t)bs * QKV_COLS + which * DMODEL + h * DHEAD + lane];
  float out;
  if (which == 2) {
    out = v;
  } else {
    float ss = v * v;
#pragma unroll
    for (int off = 32; off > 0; off >>= 1) ss += __shfl_xor(ss, off, 64);
    float scale = 1.0f / (sqrtf(ss) + EPS);
    if (which == 0) scale *= tau[h] * 0.125f * LOG2E;  // tau/sqrt(DH) * log2e
    out = v * scale;
  }
  unsigned short* dst = (which == 0) ? Qh : (which == 1) ? Kh : Vh;
  dst[((size_t)(b * NHEAD + h) * SEQ + s) * DHEAD + lane] = f2bf(out);
}

// ---------------------------------------------------------------------------
// V transpose: Vh [BH][S][DH] -> Vt [BH][DH][S]. 64x64 LDS tiles.
// ---------------------------------------------------------------------------
__global__ __launch_bounds__(256) void vtrans_kernel(
    const unsigned short* __restrict__ Vh, unsigned short* __restrict__ Vt) {
  __shared__ unsigned short tile[64][72];
  const int bh = blockIdx.x;
  const int s0 = blockIdx.y * 64;
  const int t = threadIdx.x;
  const int sr = t >> 2;          // 0..63
  const int dc = (t & 3) * 16;    // 0,16,32,48
  const unsigned short* src = Vh + ((size_t)bh * SEQ + s0 + sr) * DHEAD + dc;
  *(bf16x8*)&tile[sr][dc]     = *(const bf16x8*)(src);
  *(bf16x8*)&tile[sr][dc + 8] = *(const bf16x8*)(src + 8);
  __syncthreads();
  const int dr = t >> 2;          // 0..63 (d row)
  const int sc = (t & 3) * 16;    // s chunk
  unsigned short buf[16];
#pragma unroll
  for (int i = 0; i < 16; ++i) buf[i] = tile[sc + i][dr];
  unsigned short* dst = Vt + ((size_t)bh * DHEAD + dr) * SEQ + s0 + sc;
  *(bf16x8*)dst       = *(const bf16x8*)buf;
  *(bf16x8*)(dst + 8) = *(const bf16x8*)(buf + 8);
}

// ---------------------------------------------------------------------------
// Causal flash attention, bf16 MFMA, key-split across waves.
// grid = 4096 blocks: bh = idx&31, qtile = 127 - idx>>5 (descending work).
// Block owns 16 q-rows (q0 = qtile*16); wave w processes key chunks
// k0 = w*64, w*64+256, ... (fixed-max softmax => partials are additive:
// no online max, no rescale; merge (o,l) once through LDS at the end).
// Per 64-key step: 8 QK MFMAs (K frags transient), exp2 softmax, per-wave
// P LDS round-trip (C->A layout), 8 PV MFMAs (V^T frags transient from
// global [BH][DH][S]). ~100 live VGPRs; __launch_bounds__(256,4) caps at
// 128 so 4 waves/SIMD stay resident (round-5 @VGPR=100 was spilling).
// ---------------------------------------------------------------------------
#define PL_STRIDE 72   // shorts; 144B rows -> uniform bank spread for b128

__global__ __launch_bounds__(256, 4) void attn_kernel(
    const unsigned short* __restrict__ Qh, const unsigned short* __restrict__ Kh,
    const unsigned short* __restrict__ Vt, const float* __restrict__ tau,
    unsigned short* __restrict__ attnb) {
  __shared__ unsigned short Pl[4][16 * PL_STRIDE];  // per-wave P: [q 0..15][key 0..63]
  __shared__ float Mo[3][4][64][4];                 // [w-1][nt][lane][reg] o partials
  __shared__ float Ml[3][64][4];                    // [w-1][lane][r] l partials

  const int idx = blockIdx.x;
  const int qtile = (SEQ / 16 - 1) - (idx >> 5);    // 127..0, heaviest first
  const int bh = idx & 31;
  const int b = bh >> 4;
  const int h = bh & 15;
  const int t = threadIdx.x;
  const int w = t >> 6;
  const int lane = t & 63;
  const int quad = lane >> 4;
  const int lr = lane & 15;
  const int q0 = qtile * 16;

  const float mh2 = tau[h] * 0.125f * LOG2E;  // fixed max in log2 units

  const unsigned short* Qp = Qh + (size_t)bh * SEQ * DHEAD;
  const unsigned short* Kp = Kh + (size_t)bh * SEQ * DHEAD;
  const unsigned short* Vp = Vt + (size_t)bh * DHEAD * SEQ;
  unsigned short* Pw = &Pl[w][0];

  // Q fragments: rows q0+lr, two 32-d halves (same for all 4 waves).
  const bf16x8 aq0 = *(const bf16x8*)(Qp + (size_t)(q0 + lr) * DHEAD + quad * 8);
  const bf16x8 aq1 = *(const bf16x8*)(Qp + (size_t)(q0 + lr) * DHEAD + 32 + quad * 8);

  const f32x4 zero4 = {0.f, 0.f, 0.f, 0.f};
  f32x4 o[4];
  o[0] = o[1] = o[2] = o[3] = zero4;
  float l_[4] = {0.f, 0.f, 0.f, 0.f};

  for (int k0 = w * 64; k0 <= q0 + 15; k0 += 256) {
    const bool last = (k0 + 63 > q0);   // only chunk that can cross the diagonal
    // --- QK^T: 4 key-tiles of 16, K frags transient ---
    f32x4 c[4];
#pragma unroll
    for (int kt = 0; kt < 4; ++kt) {
      const unsigned short* kr = Kp + (size_t)(k0 + kt * 16 + lr) * DHEAD;
      const bf16x8 b0 = *(const bf16x8*)(kr + quad * 8);
      const bf16x8 b1 = *(const bf16x8*)(kr + 32 + quad * 8);
      f32x4 cc = __builtin_amdgcn_mfma_f32_16x16x32_bf16(aq0, b0, zero4, 0, 0, 0);
      c[kt] = __builtin_amdgcn_mfma_f32_16x16x32_bf16(aq1, b1, cc, 0, 0, 0);
    }
    // --- fixed-max softmax (exp2), write P to per-wave LDS ---
#pragma unroll
    for (int r = 0; r < 4; ++r) {
      const int qrow = q0 + quad * 4 + r;
      float ps = 0.f;
#pragma unroll
      for (int kt = 0; kt < 4; ++kt) {
        const int key = k0 + kt * 16 + lr;
        float p = exp2f(c[kt][r] - mh2);
        if (last) p = (key <= qrow) ? p : 0.f;
        ps += p;
        Pw[(quad * 4 + r) * PL_STRIDE + kt * 16 + lr] = f2bf(p);
      }
      l_[r] += ps;
    }
    // --- PV: pa from LDS (A layout), V^T frags transient from global ---
#pragma unroll
    for (int c2 = 0; c2 < 2; ++c2) {
      const bf16x8 pa = *(const bf16x8*)&Pw[lr * PL_STRIDE + c2 * 32 + quad * 8];
#pragma unroll
      for (int nt = 0; nt < 4; ++nt) {
        const bf16x8 vb = *(const bf16x8*)(
            Vp + (size_t)(nt * 16 + lr) * SEQ + k0 + c2 * 32 + quad * 8);
        o[nt] = __builtin_amdgcn_mfma_f32_16x16x32_bf16(pa, vb, o[nt], 0, 0, 0);
      }
    }
  }

  // --- merge partials across waves (additive: fixed max) ---
  if (w != 0) {
#pragma unroll
    for (int nt = 0; nt < 4; ++nt) *(f32x4*)&Mo[w - 1][nt][lane][0] = o[nt];
#pragma unroll
    for (int r = 0; r < 4; ++r) Ml[w - 1][lane][r] = l_[r];
  }
  __syncthreads();
  if (w == 0) {
#pragma unroll
    for (int ww = 0; ww < 3; ++ww) {
#pragma unroll
      for (int nt = 0; nt < 4; ++nt) o[nt] += *(const f32x4*)&Mo[ww][nt][lane][0];
#pragma unroll
      for (int r = 0; r < 4; ++r) l_[r] += Ml[ww][lane][r];
    }
    // reduce l across the 16-lane col group, normalize, write bf16
#pragma unroll
    for (int r = 0; r < 4; ++r) {
      float lv = l_[r];
      lv += __shfl_xor(lv, 1, 16);
      lv += __shfl_xor(lv, 2, 16);
      lv += __shfl_xor(lv, 4, 16);
      lv += __shfl_xor(lv, 8, 16);
      const float inv = 1.0f / lv;
      const int qrow = q0 + quad * 4 + r;
      unsigned short* ar = attnb + ((size_t)(b * SEQ + qrow)) * DMODEL + h * DHEAD;
#pragma unroll
      for (int nt = 0; nt < 4; ++nt) ar[nt * 16 + lr] = f2bf(o[nt][r] * inv);
    }
  }
}

// ---------------------------------------------------------------------------
// Launch
// ---------------------------------------------------------------------------
extern "C" void kernel_launch(void* const* d_in, const int* in_sizes, int n_in,
                              void* d_out, int out_size, void* d_ws, size_t ws_size,
                              hipStream_t stream) {
  const float* x    = (const float*)d_in[0];
  // d_in[1]: fixed causal tril mask -> handled analytically, never read.
  const float* Wqkv = (const float*)d_in[2];
  const float* Wo   = (const float*)d_in[3];
  const float* tau  = (const float*)d_in[4];
  float* out = (float*)d_out;

  // workspace layout (92.3 MB, unchanged footprint; aliases reuse dead bufs):
  float* qkv = (float*)d_ws;                                    // [B,S,3D] f32
  unsigned short* attnb = (unsigned short*)d_ws;                // aliases dead qkv
  unsigned short* Qh = (unsigned short*)(qkv + (size_t)BATCH * SEQ * QKV_COLS);
  unsigned short* Kh = Qh + (size_t)BATCH * NHEAD * SEQ * DHEAD;
  unsigned short* Vh = Kh + (size_t)BATCH * NHEAD * SEQ * DHEAD;
  unsigned short* Xb = Vh + (size_t)BATCH * NHEAD * SEQ * DHEAD;      // bf16 [B*S][D]
  unsigned short* Vt = Xb;                                            // aliases dead Xb
  unsigned short* Wqkv_t = Xb + (size_t)BATCH * SEQ * DMODEL;         // bf16 [3D][D]
  unsigned short* Wo_t = Wqkv_t + (size_t)DMODEL * QKV_COLS;          // bf16 [D][D]

  const int M = BATCH * SEQ;  // 4096

  // 0) prep: bf16 conversions + weight transposes
  convert_x_kernel<<<(M * DMODEL) / (256 * 4), 256, 0, stream>>>(x, Xb);
  transpose_w_kernel<<<dim3(QKV_COLS / 32, DMODEL / 32), dim3(32, 8), 0, stream>>>(
      Wqkv, Wqkv_t, DMODEL, QKV_COLS);
  transpose_w_kernel<<<dim3(DMODEL / 32, DMODEL / 32), dim3(32, 8), 0, stream>>>(
      Wo, Wo_t, DMODEL, DMODEL);

  // 1) qkv = x @ Wqkv   (M=4096, N=3072, K=1024), f32 out
  sgemm_bf16_kernel<<<dim3(QKV_COLS / 128, M / 128), 256, 0, stream>>>(
      Xb, Wqkv_t, qkv, M, QKV_COLS, DMODEL);

  // 2) qk-norm -> bf16 head-major Q/K/V (Q pre-scaled by tau/8*log2e)
  qknorm_kernel<<<dim3(BATCH * SEQ, 12), 256, 0, stream>>>(qkv, tau, Qh, Kh, Vh);

  // 3) V -> V^T [BH][DH][S]   (Xb is dead after GEMM1)
  vtrans_kernel<<<dim3(BATCH * NHEAD, SEQ / 64), 256, 0, stream>>>(Vh, Vt);

  // 4) causal MFMA flash attention -> attnb bf16 [B,S,D] (aliases dead qkv)
  attn_kernel<<<dim3(BATCH * NHEAD * SEQ / 16), 256, 0, stream>>>(
      Qh, Kh, Vt, tau, attnb);

  // 5) out = attn @ Wo  (M=4096, N=1024, K=1024), f32 out
  sgemm_bf16_kernel<<<dim3(DMODEL / 128, M / 128), 256, 0, stream>>>(
      attnb, Wo_t, out, M, DMODEL, DMODEL);
}

// Round 7
// 265.076 us; speedup vs baseline: 1.3004x; 1.2157x over previous
//
#include <hip/hip_runtime.h>
#include <math.h>

// Problem constants (from reference): B=2, S=2048, D=1024, H=16, DH=64
#define BATCH 2
#define SEQ 2048
#define DMODEL 1024
#define NHEAD 16
#define DHEAD 64
#define QKV_COLS (3 * DMODEL)          // 3072
#define EPS 1e-8f
#define LOG2E 1.44269504f

typedef short bf16x8 __attribute__((ext_vector_type(8)));   // 8 bf16 (4 VGPRs)
typedef float f32x4 __attribute__((ext_vector_type(4)));    // 4 fp32 acc

// round-to-nearest-even float -> bf16 (as raw ushort)
static __device__ __forceinline__ unsigned short f2bf(float x) {
  unsigned u = __float_as_uint(x);
  u += 0x7fffu + ((u >> 16) & 1u);
  return (unsigned short)(u >> 16);
}

// async global->LDS, 16 B per lane (global_load_lds_dwordx4).
// LDS dest: wave-uniform base + lane*16 (m104/m108).
static __device__ __forceinline__ void async_ld16(const unsigned short* g,
                                                  unsigned short* l) {
  __builtin_amdgcn_global_load_lds(
      (const __attribute__((address_space(1))) void*)g,
      (__attribute__((address_space(3))) void*)(unsigned int)(unsigned long long)l,
      16, 0, 0);
}

// ---------------------------------------------------------------------------
// Prep 1: x f32 [M][K] -> bf16 same layout. 4 floats/thread.
// ---------------------------------------------------------------------------
__global__ __launch_bounds__(256) void convert_x_kernel(
    const float* __restrict__ x, unsigned short* __restrict__ xb) {
  const size_t i = ((size_t)blockIdx.x * 256 + threadIdx.x) * 4;
  const float4 a = *(const float4*)(x + i);
  ushort4 r;
  r.x = f2bf(a.x); r.y = f2bf(a.y); r.z = f2bf(a.z); r.w = f2bf(a.w);
  *(ushort4*)(xb + i) = r;
}

// ---------------------------------------------------------------------------
// Prep 2: W f32 [K][N] -> Wt bf16 [N][K] (transposed), 32x32 LDS tiles.
// ---------------------------------------------------------------------------
__global__ __launch_bounds__(256) void transpose_w_kernel(
    const float* __restrict__ W, unsigned short* __restrict__ Wt, int K, int N) {
  __shared__ float tile[32][33];
  const int n0 = blockIdx.x * 32;
  const int k0 = blockIdx.y * 32;
  const int tx = threadIdx.x, ty = threadIdx.y;
#pragma unroll
  for (int i = 0; i < 4; ++i)
    tile[ty + i * 8][tx] = W[(size_t)(k0 + ty + i * 8) * N + n0 + tx];
  __syncthreads();
#pragma unroll
  for (int i = 0; i < 4; ++i)
    Wt[(size_t)(n0 + ty + i * 8) * K + k0 + tx] = f2bf(tile[tx][ty + i * 8]);
}

// ---------------------------------------------------------------------------
// bf16 MFMA GEMM (m97-style): C[M,N] f32 = A[M,K]bf16 @ Bt[N,K]bf16^T.
// ---------------------------------------------------------------------------
__global__ __launch_bounds__(256) void sgemm_bf16_kernel(
    const unsigned short* __restrict__ A, const unsigned short* __restrict__ Bt,
    float* __restrict__ C, int M, int N, int K) {
  __shared__ unsigned short As[128 * 32];   // [m][k] tile, row-major
  __shared__ unsigned short Bs[128 * 32];   // [n][k] tile, row-major

  const int t = threadIdx.x;
  const int w = t >> 6;
  const int lane = t & 63;
  const int quad = lane >> 4;
  const int lr = lane & 15;
  const int wr = w >> 1, wc = w & 1;
  const int m0 = blockIdx.y * 128;
  const int n0 = blockIdx.x * 128;

  const int srow = w * 32 + (lane >> 2);
  const int scol = (lane & 3) * 8;
  const unsigned short* ga = A + (size_t)(m0 + srow) * K + scol;
  const unsigned short* gb = Bt + (size_t)(n0 + srow) * K + scol;
  unsigned short* la = &As[(w * 32) * 32];
  unsigned short* lb = &Bs[(w * 32) * 32];

  f32x4 acc[4][4];
  const f32x4 zero4 = {0.f, 0.f, 0.f, 0.f};
#pragma unroll
  for (int i = 0; i < 4; ++i)
#pragma unroll
    for (int j = 0; j < 4; ++j) acc[i][j] = zero4;

  for (int k0 = 0; k0 < K; k0 += 32) {
#pragma unroll
    for (int i = 0; i < 2; ++i) {
      async_ld16(ga + (size_t)(i * 16) * K + k0, la + i * 16 * 32);
      async_ld16(gb + (size_t)(i * 16) * K + k0, lb + i * 16 * 32);
    }
    __syncthreads();

    bf16x8 af[4], bf[4];
#pragma unroll
    for (int i = 0; i < 4; ++i)
      af[i] = *(const bf16x8*)&As[(wr * 64 + i * 16 + lr) * 32 + quad * 8];
#pragma unroll
    for (int j = 0; j < 4; ++j)
      bf[j] = *(const bf16x8*)&Bs[(wc * 64 + j * 16 + lr) * 32 + quad * 8];
#pragma unroll
    for (int i = 0; i < 4; ++i)
#pragma unroll
      for (int j = 0; j < 4; ++j)
        acc[i][j] = __builtin_amdgcn_mfma_f32_16x16x32_bf16(af[i], bf[j], acc[i][j], 0, 0, 0);
    __syncthreads();
  }

#pragma unroll
  for (int i = 0; i < 4; ++i)
#pragma unroll
    for (int r = 0; r < 4; ++r) {
      float* c = C + (size_t)(m0 + wr * 64 + i * 16 + quad * 4 + r) * N + n0 + wc * 64 + lr;
#pragma unroll
      for (int j = 0; j < 4; ++j) c[j * 16] = acc[i][j][r];
    }
}

// ---------------------------------------------------------------------------
// qknorm: read qkv f32 [B,S,3D]; L2-normalize q,k per head; fold
// tau/sqrt(DH) * log2(e) into q (so attention uses exp2); emit bf16 Q/K/V
// head-major [B,H,S,DH].
// ---------------------------------------------------------------------------
__global__ __launch_bounds__(256) void qknorm_kernel(
    const float* __restrict__ qkv, const float* __restrict__ tau,
    unsigned short* __restrict__ Qh, unsigned short* __restrict__ Kh,
    unsigned short* __restrict__ Vh) {
  const int lane = threadIdx.x & 63;
  const int widx = blockIdx.y * 4 + (threadIdx.x >> 6);  // 0..47
  const int which = widx >> 4;                           // 0=q, 1=k, 2=v
  const int h = widx & 15;
  const int bs = blockIdx.x;
  const int b = bs >> 11;
  const int s = bs & 2047;

  const float v = qkv[(size_t)bs * QKV_COLS + which * DMODEL + h * DHEAD + lane];
  float out;
  if (which == 2) {
    out = v;
  } else {
    float ss = v * v;
#pragma unroll
    for (int off = 32; off > 0; off >>= 1) ss += __shfl_xor(ss, off, 64);
    float scale = 1.0f / (sqrtf(ss) + EPS);
    if (which == 0) scale *= tau[h] * 0.125f * LOG2E;  // tau/sqrt(DH) * log2e
    out = v * scale;
  }
  unsigned short* dst = (which == 0) ? Qh : (which == 1) ? Kh : Vh;
  dst[((size_t)(b * NHEAD + h) * SEQ + s) * DHEAD + lane] = f2bf(out);
}

// ---------------------------------------------------------------------------
// V transpose: Vh [BH][S][DH] -> Vt [BH][DH][S]. 64x64 LDS tiles.
// ---------------------------------------------------------------------------
__global__ __launch_bounds__(256) void vtrans_kernel(
    const unsigned short* __restrict__ Vh, unsigned short* __restrict__ Vt) {
  __shared__ unsigned short tile[64][72];
  const int bh = blockIdx.x;
  const int s0 = blockIdx.y * 64;
  const int t = threadIdx.x;
  const int sr = t >> 2;          // 0..63
  const int dc = (t & 3) * 16;    // 0,16,32,48
  const unsigned short* src = Vh + ((size_t)bh * SEQ + s0 + sr) * DHEAD + dc;
  *(bf16x8*)&tile[sr][dc]     = *(const bf16x8*)(src);
  *(bf16x8*)&tile[sr][dc + 8] = *(const bf16x8*)(src + 8);
  __syncthreads();
  const int dr = t >> 2;          // 0..63 (d row)
  const int sc = (t & 3) * 16;    // s chunk
  unsigned short buf[16];
#pragma unroll
  for (int i = 0; i < 16; ++i) buf[i] = tile[sc + i][dr];
  unsigned short* dst = Vt + ((size_t)bh * DHEAD + dr) * SEQ + s0 + sc;
  *(bf16x8*)dst       = *(const bf16x8*)buf;
  *(bf16x8*)(dst + 8) = *(const bf16x8*)(buf + 8);
}

// ---------------------------------------------------------------------------
// Causal flash attention, bf16 MFMA, LDS-tiled K/V (double-buffered async
// staging like the GEMM) to cut L2 re-read traffic 8x (R4-R6 plateaued at
// ~1.08 GB of global K/V re-reads ~ 8 TB/s fabric ceiling).
// grid = 512: bh = idx&31, qblk = 15 - idx>>5 (128 q-rows per block,
// descending work). 4 waves; wave w owns q-tiles qblk*128 + w*16 (+64).
//
// OPERAND SWAP: QK^T computed as S^T = K*Q^T (A=K-frag, B=Q-frag; layouts
// symmetric). C layout then gives lane (quad,lr): S[q=lr][key=quad*4+r] --
// 4 CONSECUTIVE keys per lane -> P written as one ds_write_b64 per kt,
// l is a per-lane scalar (2 shuffles at epilogue only). PV: A=P (readback,
// row lr contiguous), B=V^T frags from LDS tile -> O in C layout
// [q=quad*4+r][d=lr].
// ---------------------------------------------------------------------------
#define PLS 72   // P row stride in shorts (144 B)

__global__ __launch_bounds__(256, 3) void attn_kernel(
    const unsigned short* __restrict__ Qh, const unsigned short* __restrict__ Kh,
    const unsigned short* __restrict__ Vt, const float* __restrict__ tau,
    unsigned short* __restrict__ attnb) {
  __shared__ unsigned short Ks[2][2][64 * 32];   // [buf][d-half][key*32 + d']
  __shared__ unsigned short Vs[2][2][64 * 32];   // [buf][key-half][d*32 + key']
  __shared__ unsigned short Pl[4][2][16 * PLS];  // [wave][qt][q*PLS + key]

  const int idx = blockIdx.x;
  const int qblk = (SEQ / 128 - 1) - (idx >> 5);  // 15..0, heaviest first
  const int bh = idx & 31;
  const int b = bh >> 4;
  const int h = bh & 15;
  const int t = threadIdx.x;
  const int w = t >> 6;
  const int lane = t & 63;
  const int quad = lane >> 4;
  const int lr = lane & 15;
  const int q0 = qblk * 128;
  const int kend = q0 + 128;

  const float mh2 = tau[h] * 0.125f * LOG2E;  // fixed softmax max (log2 units)

  const unsigned short* Qp = Qh + (size_t)bh * SEQ * DHEAD;
  const unsigned short* Kp = Kh + (size_t)bh * SEQ * DHEAD;
  const unsigned short* Vp = Vt + (size_t)bh * DHEAD * SEQ;

  // staging geometry: 16 async_ld16 per step (8 K + 8 V), wave w issues 4.
  const int srow = lane >> 2;        // 0..15 row within 16-row group
  const int scol = (lane & 3) * 8;   // shorts: 16B segment within 32-short row
  const int f0 = w * 4;

  auto stage = [&](int k0, int bb) {
#pragma unroll
    for (int i = 0; i < 4; ++i) {
      const int fi = f0 + i;
      if (fi < 8) {   // K half-tiles: [key][32 d'], rows 64B
        const int hh = fi >> 2, seg = fi & 3;
        async_ld16(Kp + (size_t)(k0 + seg * 16 + srow) * DHEAD + hh * 32 + scol,
                   &Ks[bb][hh][seg * 512]);
      } else {        // V^T half-tiles: [d][32 key'], rows 64B
        const int g = fi - 8;
        const int cc = g >> 2, seg = g & 3;
        async_ld16(Vp + (size_t)(seg * 16 + srow) * SEQ + k0 + cc * 32 + scol,
                   &Vs[bb][cc][seg * 512]);
      }
    }
  };

  const int qb0 = q0 + w * 16;        // q-tile 0 (dies on late steps)
  const int qb1 = q0 + 64 + w * 16;   // q-tile 1 (alive all steps)

  // Q fragments (B-operand): lane holds Q[qb+lr][d = half*32 + quad*8 + j]
  bf16x8 aq[2][2];
#pragma unroll
  for (int qt = 0; qt < 2; ++qt) {
    const unsigned short* qr = Qp + (size_t)((qt ? qb1 : qb0) + lr) * DHEAD;
    aq[qt][0] = *(const bf16x8*)(qr + quad * 8);
    aq[qt][1] = *(const bf16x8*)(qr + 32 + quad * 8);
  }

  const f32x4 zero4 = {0.f, 0.f, 0.f, 0.f};
  f32x4 o[2][4];
#pragma unroll
  for (int qt = 0; qt < 2; ++qt)
#pragma unroll
    for (int nt = 0; nt < 4; ++nt) o[qt][nt] = zero4;
  float l0 = 0.f, l1 = 0.f;

  // softmax + packed-b64 P write for one q-tile
#define SOFTMAX_P(cArr, Pq, lAcc, qbt)                                       \
  do {                                                                       \
    const bool msk = (k0 + 63 > (qbt));                                      \
    const int qrow = (qbt) + lr;                                             \
    float ps = 0.f;                                                          \
    _Pragma("unroll")                                                        \
    for (int kt = 0; kt < 4; ++kt) {                                         \
      unsigned short pk[4];                                                  \
      _Pragma("unroll")                                                      \
      for (int r = 0; r < 4; ++r) {                                          \
        const int key = k0 + kt * 16 + quad * 4 + r;                         \
        float p = exp2f(cArr[kt][r] - mh2);                                  \
        if (msk && key > qrow) p = 0.f;                                      \
        ps += p;                                                             \
        pk[r] = f2bf(p);                                                     \
      }                                                                      \
      *(unsigned long long*)&(Pq)[lr * PLS + kt * 16 + quad * 4] =           \
          *(const unsigned long long*)pk;                                    \
    }                                                                        \
    lAcc += ps;                                                              \
  } while (0)

  stage(0, 0);
  int bb = 0;
  for (int k0 = 0; k0 < kend; k0 += 64, bb ^= 1) {
    __syncthreads();                       // buf bb staged; prev reads done
    if (k0 + 64 < kend) stage(k0 + 64, bb ^ 1);

    const bool a0 = (k0 <= qb0 + 15);      // wave-uniform: q-tile 0 alive

    // --- QK^T (swapped): A = K frag, B = Q frag; chain the two 32-d halves
    f32x4 c0[4], c1[4];
#pragma unroll
    for (int kt = 0; kt < 4; ++kt) {
      const bf16x8 kf0 = *(const bf16x8*)&Ks[bb][0][(kt * 16 + lr) * 32 + quad * 8];
      const bf16x8 kf1 = *(const bf16x8*)&Ks[bb][1][(kt * 16 + lr) * 32 + quad * 8];
      if (a0) {
        f32x4 tt = __builtin_amdgcn_mfma_f32_16x16x32_bf16(kf0, aq[0][0], zero4, 0, 0, 0);
        c0[kt] = __builtin_amdgcn_mfma_f32_16x16x32_bf16(kf1, aq[0][1], tt, 0, 0, 0);
      }
      f32x4 tt1 = __builtin_amdgcn_mfma_f32_16x16x32_bf16(kf0, aq[1][0], zero4, 0, 0, 0);
      c1[kt] = __builtin_amdgcn_mfma_f32_16x16x32_bf16(kf1, aq[1][1], tt1, 0, 0, 0);
    }

    // --- fixed-max exp2 softmax, b64 P writes, per-lane l accumulate
    if (a0) SOFTMAX_P(c0, Pl[w][0], l0, qb0);
    SOFTMAX_P(c1, Pl[w][1], l1, qb1);

    // --- PV: A = P readback (row lr, contiguous keys), B = V^T frags
    bf16x8 vb[2][4];
#pragma unroll
    for (int c2 = 0; c2 < 2; ++c2)
#pragma unroll
      for (int nt = 0; nt < 4; ++nt)
        vb[c2][nt] = *(const bf16x8*)&Vs[bb][c2][(nt * 16 + lr) * 32 + quad * 8];
#pragma unroll
    for (int c2 = 0; c2 < 2; ++c2) {
      if (a0) {
        const bf16x8 pa0 = *(const bf16x8*)&Pl[w][0][lr * PLS + c2 * 32 + quad * 8];
#pragma unroll
        for (int nt = 0; nt < 4; ++nt)
          o[0][nt] = __builtin_amdgcn_mfma_f32_16x16x32_bf16(pa0, vb[c2][nt], o[0][nt], 0, 0, 0);
      }
      const bf16x8 pa1 = *(const bf16x8*)&Pl[w][1][lr * PLS + c2 * 32 + quad * 8];
#pragma unroll
      for (int nt = 0; nt < 4; ++nt)
        o[1][nt] = __builtin_amdgcn_mfma_f32_16x16x32_bf16(pa1, vb[c2][nt], o[1][nt], 0, 0, 0);
    }
  }
#undef SOFTMAX_P

  // --- epilogue: l lives per-lane for q=lr; reduce across quads, broadcast
  // the right row's 1/l to the C-layout rows (q=quad*4+r), write bf16.
#pragma unroll
  for (int qt = 0; qt < 2; ++qt) {
    float lt = qt ? l1 : l0;
    lt += __shfl_xor(lt, 16, 64);
    lt += __shfl_xor(lt, 32, 64);
    const float inv = 1.0f / lt;          // valid for q = lr
    const int qbt = qt ? qb1 : qb0;
#pragma unroll
    for (int r = 0; r < 4; ++r) {
      const float invr = __shfl(inv, quad * 4 + r, 16);  // 1/l for q=quad*4+r
      unsigned short* ar =
          attnb + ((size_t)(b * SEQ + qbt + quad * 4 + r)) * DMODEL + h * DHEAD;
#pragma unroll
      for (int nt = 0; nt < 4; ++nt) ar[nt * 16 + lr] = f2bf(o[qt][nt][r] * invr);
    }
  }
}

// ---------------------------------------------------------------------------
// Launch
// ---------------------------------------------------------------------------
extern "C" void kernel_launch(void* const* d_in, const int* in_sizes, int n_in,
                              void* d_out, int out_size, void* d_ws, size_t ws_size,
                              hipStream_t stream) {
  const float* x    = (const float*)d_in[0];
  // d_in[1]: fixed causal tril mask -> handled analytically, never read.
  const float* Wqkv = (const float*)d_in[2];
  const float* Wo   = (const float*)d_in[3];
  const float* tau  = (const float*)d_in[4];
  float* out = (float*)d_out;

  // workspace layout (92.3 MB, unchanged footprint; aliases reuse dead bufs):
  float* qkv = (float*)d_ws;                                    // [B,S,3D] f32
  unsigned short* attnb = (unsigned short*)d_ws;                // aliases dead qkv
  unsigned short* Qh = (unsigned short*)(qkv + (size_t)BATCH * SEQ * QKV_COLS);
  unsigned short* Kh = Qh + (size_t)BATCH * NHEAD * SEQ * DHEAD;
  unsigned short* Vh = Kh + (size_t)BATCH * NHEAD * SEQ * DHEAD;
  unsigned short* Xb = Vh + (size_t)BATCH * NHEAD * SEQ * DHEAD;      // bf16 [B*S][D]
  unsigned short* Vt = Xb;                                            // aliases dead Xb
  unsigned short* Wqkv_t = Xb + (size_t)BATCH * SEQ * DMODEL;         // bf16 [3D][D]
  unsigned short* Wo_t = Wqkv_t + (size_t)DMODEL * QKV_COLS;          // bf16 [D][D]

  const int M = BATCH * SEQ;  // 4096

  // 0) prep: bf16 conversions + weight transposes
  convert_x_kernel<<<(M * DMODEL) / (256 * 4), 256, 0, stream>>>(x, Xb);
  transpose_w_kernel<<<dim3(QKV_COLS / 32, DMODEL / 32), dim3(32, 8), 0, stream>>>(
      Wqkv, Wqkv_t, DMODEL, QKV_COLS);
  transpose_w_kernel<<<dim3(DMODEL / 32, DMODEL / 32), dim3(32, 8), 0, stream>>>(
      Wo, Wo_t, DMODEL, DMODEL);

  // 1) qkv = x @ Wqkv   (M=4096, N=3072, K=1024), f32 out
  sgemm_bf16_kernel<<<dim3(QKV_COLS / 128, M / 128), 256, 0, stream>>>(
      Xb, Wqkv_t, qkv, M, QKV_COLS, DMODEL);

  // 2) qk-norm -> bf16 head-major Q/K/V (Q pre-scaled by tau/8*log2e)
  qknorm_kernel<<<dim3(BATCH * SEQ, 12), 256, 0, stream>>>(qkv, tau, Qh, Kh, Vh);

  // 3) V -> V^T [BH][DH][S]   (Xb is dead after GEMM1)
  vtrans_kernel<<<dim3(BATCH * NHEAD, SEQ / 64), 256, 0, stream>>>(Vh, Vt);

  // 4) causal MFMA flash attention -> attnb bf16 [B,S,D] (aliases dead qkv)
  attn_kernel<<<dim3(BATCH * NHEAD * SEQ / 128), 256, 0, stream>>>(
      Qh, Kh, Vt, tau, attnb);

  // 5) out = attn @ Wo  (M=4096, N=1024, K=1024), f32 out
  sgemm_bf16_kernel<<<dim3(DMODEL / 128, M / 128), 256, 0, stream>>>(
      attnb, Wo_t, out, M, DMODEL, DMODEL);
}

// Round 8
// 234.429 us; speedup vs baseline: 1.4705x; 1.1307x over previous
//
#include <hip/hip_runtime.h>
#include <math.h>

// Problem constants (from reference): B=2, S=2048, D=1024, H=16, DH=64
#define BATCH 2
#define SEQ 2048
#define DMODEL 1024
#define NHEAD 16
#define DHEAD 64
#define QKV_COLS (3 * DMODEL)          // 3072
#define EPS 1e-8f
#define LOG2E 1.44269504f

typedef short bf16x8 __attribute__((ext_vector_type(8)));   // 8 bf16 (4 VGPRs)
typedef float f32x4 __attribute__((ext_vector_type(4)));    // 4 fp32 acc

// round-to-nearest-even float -> bf16 (as raw ushort)
static __device__ __forceinline__ unsigned short f2bf(float x) {
  unsigned u = __float_as_uint(x);
  u += 0x7fffu + ((u >> 16) & 1u);
  return (unsigned short)(u >> 16);
}

// pack two f32 -> (bf16(hi)<<16)|bf16(lo) in 3 VALU (round-half-up + v_perm)
static __device__ __forceinline__ unsigned pkbf(float lo, float hi) {
  const unsigned ul = __float_as_uint(lo) + 0x8000u;
  const unsigned uh = __float_as_uint(hi) + 0x8000u;
  return __builtin_amdgcn_perm(uh, ul, 0x07060302);  // [uh.hi16 | ul.hi16]
}

// async global->LDS, 16 B per lane (global_load_lds_dwordx4).
// LDS dest: wave-uniform base + lane*16 (m104/m108).
static __device__ __forceinline__ void async_ld16(const unsigned short* g,
                                                  unsigned short* l) {
  __builtin_amdgcn_global_load_lds(
      (const __attribute__((address_space(1))) void*)g,
      (__attribute__((address_space(3))) void*)(unsigned int)(unsigned long long)l,
      16, 0, 0);
}

// ---------------------------------------------------------------------------
// Prep 1: x f32 [M][K] -> bf16 same layout. 4 floats/thread.
// ---------------------------------------------------------------------------
__global__ __launch_bounds__(256) void convert_x_kernel(
    const float* __restrict__ x, unsigned short* __restrict__ xb) {
  const size_t i = ((size_t)blockIdx.x * 256 + threadIdx.x) * 4;
  const float4 a = *(const float4*)(x + i);
  ushort4 r;
  r.x = f2bf(a.x); r.y = f2bf(a.y); r.z = f2bf(a.z); r.w = f2bf(a.w);
  *(ushort4*)(xb + i) = r;
}

// ---------------------------------------------------------------------------
// Prep 2: W f32 [K][N] -> Wt bf16 [N][K] (transposed), 32x32 LDS tiles.
// ---------------------------------------------------------------------------
__global__ __launch_bounds__(256) void transpose_w_kernel(
    const float* __restrict__ W, unsigned short* __restrict__ Wt, int K, int N) {
  __shared__ float tile[32][33];
  const int n0 = blockIdx.x * 32;
  const int k0 = blockIdx.y * 32;
  const int tx = threadIdx.x, ty = threadIdx.y;
#pragma unroll
  for (int i = 0; i < 4; ++i)
    tile[ty + i * 8][tx] = W[(size_t)(k0 + ty + i * 8) * N + n0 + tx];
  __syncthreads();
#pragma unroll
  for (int i = 0; i < 4; ++i)
    Wt[(size_t)(n0 + ty + i * 8) * K + k0 + tx] = f2bf(tile[tx][ty + i * 8]);
}

// ---------------------------------------------------------------------------
// bf16 MFMA GEMM (m97-style): C[M,N] f32 = A[M,K]bf16 @ Bt[N,K]bf16^T.
// Used for GEMM2 (out = attn @ Wo).
// ---------------------------------------------------------------------------
__global__ __launch_bounds__(256) void sgemm_bf16_kernel(
    const unsigned short* __restrict__ A, const unsigned short* __restrict__ Bt,
    float* __restrict__ C, int M, int N, int K) {
  __shared__ unsigned short As[128 * 32];   // [m][k] tile, row-major
  __shared__ unsigned short Bs[128 * 32];   // [n][k] tile, row-major

  const int t = threadIdx.x;
  const int w = t >> 6;
  const int lane = t & 63;
  const int quad = lane >> 4;
  const int lr = lane & 15;
  const int wr = w >> 1, wc = w & 1;
  const int m0 = blockIdx.y * 128;
  const int n0 = blockIdx.x * 128;

  const int srow = w * 32 + (lane >> 2);
  const int scol = (lane & 3) * 8;
  const unsigned short* ga = A + (size_t)(m0 + srow) * K + scol;
  const unsigned short* gb = Bt + (size_t)(n0 + srow) * K + scol;
  unsigned short* la = &As[(w * 32) * 32];
  unsigned short* lb = &Bs[(w * 32) * 32];

  f32x4 acc[4][4];
  const f32x4 zero4 = {0.f, 0.f, 0.f, 0.f};
#pragma unroll
  for (int i = 0; i < 4; ++i)
#pragma unroll
    for (int j = 0; j < 4; ++j) acc[i][j] = zero4;

  for (int k0 = 0; k0 < K; k0 += 32) {
#pragma unroll
    for (int i = 0; i < 2; ++i) {
      async_ld16(ga + (size_t)(i * 16) * K + k0, la + i * 16 * 32);
      async_ld16(gb + (size_t)(i * 16) * K + k0, lb + i * 16 * 32);
    }
    __syncthreads();

    bf16x8 af[4], bf[4];
#pragma unroll
    for (int i = 0; i < 4; ++i)
      af[i] = *(const bf16x8*)&As[(wr * 64 + i * 16 + lr) * 32 + quad * 8];
#pragma unroll
    for (int j = 0; j < 4; ++j)
      bf[j] = *(const bf16x8*)&Bs[(wc * 64 + j * 16 + lr) * 32 + quad * 8];
#pragma unroll
    for (int i = 0; i < 4; ++i)
#pragma unroll
      for (int j = 0; j < 4; ++j)
        acc[i][j] = __builtin_amdgcn_mfma_f32_16x16x32_bf16(af[i], bf[j], acc[i][j], 0, 0, 0);
    __syncthreads();
  }

#pragma unroll
  for (int i = 0; i < 4; ++i)
#pragma unroll
    for (int r = 0; r < 4; ++r) {
      float* c = C + (size_t)(m0 + wr * 64 + i * 16 + quad * 4 + r) * N + n0 + wc * 64 + lr;
#pragma unroll
      for (int j = 0; j < 4; ++j) c[j * 16] = acc[i][j][r];
    }
}

// ---------------------------------------------------------------------------
// GEMM1 + fused qk-norm: qkv = Xb @ Wqkv_t^T, then per-row L2 norm of the
// wave's 64-col sub-tile (exactly one (which,head) since col0 = n0 + wc*64 is
// a multiple of 64), fold tau/sqrt(DH)*log2e into Q, write bf16 directly to
// Qh/Kh/Vh [B,H,S,DH]. Wave's C sub-tile covers the FULL head dim (64 cols):
// sumsq = 4 local squares + 4 shuffles per row. No f32 qkv round-trip.
// ---------------------------------------------------------------------------
__global__ __launch_bounds__(256) void qkv_gemm_norm_kernel(
    const unsigned short* __restrict__ A, const unsigned short* __restrict__ Bt,
    const float* __restrict__ tau,
    unsigned short* __restrict__ Qh, unsigned short* __restrict__ Kh,
    unsigned short* __restrict__ Vh) {
  __shared__ unsigned short As[128 * 32];
  __shared__ unsigned short Bs[128 * 32];

  const int K = DMODEL, N = QKV_COLS;
  const int t = threadIdx.x;
  const int w = t >> 6;
  const int lane = t & 63;
  const int quad = lane >> 4;
  const int lr = lane & 15;
  const int wr = w >> 1, wc = w & 1;
  const int m0 = blockIdx.y * 128;
  const int n0 = blockIdx.x * 128;

  const int srow = w * 32 + (lane >> 2);
  const int scol = (lane & 3) * 8;
  const unsigned short* ga = A + (size_t)(m0 + srow) * K + scol;
  const unsigned short* gb = Bt + (size_t)(n0 + srow) * K + scol;
  unsigned short* la = &As[(w * 32) * 32];
  unsigned short* lb = &Bs[(w * 32) * 32];

  f32x4 acc[4][4];
  const f32x4 zero4 = {0.f, 0.f, 0.f, 0.f};
#pragma unroll
  for (int i = 0; i < 4; ++i)
#pragma unroll
    for (int j = 0; j < 4; ++j) acc[i][j] = zero4;

  for (int k0 = 0; k0 < K; k0 += 32) {
#pragma unroll
    for (int i = 0; i < 2; ++i) {
      async_ld16(ga + (size_t)(i * 16) * K + k0, la + i * 16 * 32);
      async_ld16(gb + (size_t)(i * 16) * K + k0, lb + i * 16 * 32);
    }
    __syncthreads();

    bf16x8 af[4], bf[4];
#pragma unroll
    for (int i = 0; i < 4; ++i)
      af[i] = *(const bf16x8*)&As[(wr * 64 + i * 16 + lr) * 32 + quad * 8];
#pragma unroll
    for (int j = 0; j < 4; ++j)
      bf[j] = *(const bf16x8*)&Bs[(wc * 64 + j * 16 + lr) * 32 + quad * 8];
#pragma unroll
    for (int i = 0; i < 4; ++i)
#pragma unroll
      for (int j = 0; j < 4; ++j)
        acc[i][j] = __builtin_amdgcn_mfma_f32_16x16x32_bf16(af[i], bf[j], acc[i][j], 0, 0, 0);
    __syncthreads();
  }

  // Epilogue: wave-uniform (which, head) from column block.
  const int col0 = n0 + wc * 64;
  const int which = col0 >> 10;             // 0=q, 1=k, 2=v
  const int h = (col0 & 1023) >> 6;
  const float tsc = tau[h] * 0.125f * LOG2E;
  unsigned short* dst = (which == 0) ? Qh : (which == 1) ? Kh : Vh;

#pragma unroll
  for (int i = 0; i < 4; ++i)
#pragma unroll
    for (int r = 0; r < 4; ++r) {
      const int s = m0 + wr * 64 + i * 16 + quad * 4 + r;   // global row 0..4095
      unsigned short* ar =
          dst + (((size_t)((s >> 11) * NHEAD + h)) * SEQ + (s & 2047)) * DHEAD;
      float scale;
      if (which == 2) {
        scale = 1.0f;
      } else {
        float ss = 0.f;
#pragma unroll
        for (int j = 0; j < 4; ++j) ss += acc[i][j][r] * acc[i][j][r];
        ss += __shfl_xor(ss, 1, 16);
        ss += __shfl_xor(ss, 2, 16);
        ss += __shfl_xor(ss, 4, 16);
        ss += __shfl_xor(ss, 8, 16);
        scale = 1.0f / (sqrtf(ss) + EPS);
        if (which == 0) scale *= tsc;       // tau/sqrt(DH) * log2e into Q
      }
#pragma unroll
      for (int j = 0; j < 4; ++j) ar[j * 16 + lr] = f2bf(acc[i][j][r] * scale);
    }
}

// ---------------------------------------------------------------------------
// V transpose: Vh [BH][S][DH] -> Vt [BH][DH][S]. 64x64 LDS tiles.
// ---------------------------------------------------------------------------
__global__ __launch_bounds__(256) void vtrans_kernel(
    const unsigned short* __restrict__ Vh, unsigned short* __restrict__ Vt) {
  __shared__ unsigned short tile[64][72];
  const int bh = blockIdx.x;
  const int s0 = blockIdx.y * 64;
  const int t = threadIdx.x;
  const int sr = t >> 2;          // 0..63
  const int dc = (t & 3) * 16;    // 0,16,32,48
  const unsigned short* src = Vh + ((size_t)bh * SEQ + s0 + sr) * DHEAD + dc;
  *(bf16x8*)&tile[sr][dc]     = *(const bf16x8*)(src);
  *(bf16x8*)&tile[sr][dc + 8] = *(const bf16x8*)(src + 8);
  __syncthreads();
  const int dr = t >> 2;          // 0..63 (d row)
  const int sc = (t & 3) * 16;    // s chunk
  unsigned short buf[16];
#pragma unroll
  for (int i = 0; i < 16; ++i) buf[i] = tile[sc + i][dr];
  unsigned short* dst = Vt + ((size_t)bh * DHEAD + dr) * SEQ + s0 + sc;
  *(bf16x8*)dst       = *(const bf16x8*)buf;
  *(bf16x8*)(dst + 8) = *(const bf16x8*)(buf + 8);
}

// ---------------------------------------------------------------------------
// Causal flash attention, bf16 MFMA, LDS-tiled K/V double-buffered (R7),
// with R8 VALU cuts:
//  - fixed-max exp2 WITHOUT the -mh2 subtract (cancels in o/l; |logit| small)
//  - causal mask only on the provably-diagonal step (wave-uniform branch)
//  - P packed via v_perm (+0x8000 round-half-up), 2 elems / 3 VALU
//  - dispatch pairing: block c and block 256+c have step counts summing to a
//    constant, so each CU's two resident blocks carry equal total work.
// grid = 512; 4 waves; wave w owns q-tiles qblk*128 + w*16 (+64).
// Operand-swapped S^T = K*Q^T (lane holds 4 consecutive keys -> b64 P write,
// per-lane scalar l). PV: A = P readback, B = V^T from LDS tile.
// ---------------------------------------------------------------------------
#define PLS 72   // P row stride in shorts (144 B)

__global__ __launch_bounds__(256, 2) void attn_kernel(
    const unsigned short* __restrict__ Qh, const unsigned short* __restrict__ Kh,
    const unsigned short* __restrict__ Vt, unsigned short* __restrict__ attnb) {
  __shared__ unsigned short Ks[2][2][64 * 32];   // [buf][d-half][key*32 + d']
  __shared__ unsigned short Vs[2][2][64 * 32];   // [buf][key-half][d*32 + key']
  __shared__ unsigned short Pl[4][2][16 * PLS];  // [wave][qt][q*PLS + key]

  const int idx = blockIdx.x;
  const int pair = idx >> 5;
  const int qblk = (idx < 256) ? (15 - pair) : (pair - 8);  // pairs sum to 17 steps
  const int bh = idx & 31;
  const int b = bh >> 4;
  const int h = bh & 15;
  const int t = threadIdx.x;
  const int w = t >> 6;
  const int lane = t & 63;
  const int quad = lane >> 4;
  const int lr = lane & 15;
  const int q0 = qblk * 128;
  const int kend = q0 + 128;

  const unsigned short* Qp = Qh + (size_t)bh * SEQ * DHEAD;
  const unsigned short* Kp = Kh + (size_t)bh * SEQ * DHEAD;
  const unsigned short* Vp = Vt + (size_t)bh * DHEAD * SEQ;

  // staging geometry: 16 async_ld16 per step (8 K + 8 V), wave w issues 4.
  const int srow = lane >> 2;        // 0..15 row within 16-row group
  const int scol = (lane & 3) * 8;   // shorts: 16B segment within 32-short row
  const int f0 = w * 4;

  auto stage = [&](int k0, int bb) {
#pragma unroll
    for (int i = 0; i < 4; ++i) {
      const int fi = f0 + i;
      if (fi < 8) {   // K half-tiles: [key][32 d'], rows 64B
        const int hh = fi >> 2, seg = fi & 3;
        async_ld16(Kp + (size_t)(k0 + seg * 16 + srow) * DHEAD + hh * 32 + scol,
                   &Ks[bb][hh][seg * 512]);
      } else {        // V^T half-tiles: [d][32 key'], rows 64B
        const int g = fi - 8;
        const int cc = g >> 2, seg = g & 3;
        async_ld16(Vp + (size_t)(seg * 16 + srow) * SEQ + k0 + cc * 32 + scol,
                   &Vs[bb][cc][seg * 512]);
      }
    }
  };

  const int qb0 = q0 + w * 16;        // q-tile 0 (dies on late steps)
  const int qb1 = q0 + 64 + w * 16;   // q-tile 1 (alive all steps)

  // Q fragments (B-operand): lane holds Q[qb+lr][d = half*32 + quad*8 + j]
  bf16x8 aq[2][2];
#pragma unroll
  for (int qt = 0; qt < 2; ++qt) {
    const unsigned short* qr = Qp + (size_t)((qt ? qb1 : qb0) + lr) * DHEAD;
    aq[qt][0] = *(const bf16x8*)(qr + quad * 8);
    aq[qt][1] = *(const bf16x8*)(qr + 32 + quad * 8);
  }

  const f32x4 zero4 = {0.f, 0.f, 0.f, 0.f};
  f32x4 o[2][4];
#pragma unroll
  for (int qt = 0; qt < 2; ++qt)
#pragma unroll
    for (int nt = 0; nt < 4; ++nt) o[qt][nt] = zero4;
  float l0 = 0.f, l1 = 0.f;

  // softmax + packed P write for one q-tile; mask branch is wave-uniform and
  // taken only on the diagonal-crossing step.
#define SOFTMAX_P(cArr, Pq, lAcc, qbt)                                       \
  do {                                                                       \
    float ps = 0.f;                                                          \
    if (k0 + 63 > (qbt)) {                                                   \
      const int qrow = (qbt) + lr;                                           \
      _Pragma("unroll")                                                      \
      for (int kt = 0; kt < 4; ++kt) {                                       \
        float p[4];                                                          \
        _Pragma("unroll")                                                    \
        for (int r = 0; r < 4; ++r) {                                        \
          const int key = k0 + kt * 16 + quad * 4 + r;                       \
          p[r] = (key <= qrow) ? exp2f(cArr[kt][r]) : 0.f;                   \
          ps += p[r];                                                        \
        }                                                                    \
        const unsigned lo = pkbf(p[0], p[1]);                                \
        const unsigned hi = pkbf(p[2], p[3]);                                \
        *(unsigned long long*)&(Pq)[lr * PLS + kt * 16 + quad * 4] =         \
            ((unsigned long long)hi << 32) | lo;                             \
      }                                                                      \
    } else {                                                                 \
      _Pragma("unroll")                                                      \
      for (int kt = 0; kt < 4; ++kt) {                                       \
        float p[4];                                                          \
        _Pragma("unroll")                                                    \
        for (int r = 0; r < 4; ++r) {                                        \
          p[r] = exp2f(cArr[kt][r]);                                         \
          ps += p[r];                                                        \
        }                                                                    \
        const unsigned lo = pkbf(p[0], p[1]);                                \
        const unsigned hi = pkbf(p[2], p[3]);                                \
        *(unsigned long long*)&(Pq)[lr * PLS + kt * 16 + quad * 4] =         \
            ((unsigned long long)hi << 32) | lo;                             \
      }                                                                      \
    }                                                                        \
    lAcc += ps;                                                              \
  } while (0)

  stage(0, 0);
  int bb = 0;
  for (int k0 = 0; k0 < kend; k0 += 64, bb ^= 1) {
    __syncthreads();                       // buf bb staged; prev reads done
    if (k0 + 64 < kend) stage(k0 + 64, bb ^ 1);

    const bool a0 = (k0 <= qb0 + 15);      // wave-uniform: q-tile 0 alive

    // --- QK^T (swapped): A = K frag, B = Q frag; chain the two 32-d halves
    f32x4 c0[4], c1[4];
#pragma unroll
    for (int kt = 0; kt < 4; ++kt) {
      const bf16x8 kf0 = *(const bf16x8*)&Ks[bb][0][(kt * 16 + lr) * 32 + quad * 8];
      const bf16x8 kf1 = *(const bf16x8*)&Ks[bb][1][(kt * 16 + lr) * 32 + quad * 8];
      if (a0) {
        f32x4 tt = __builtin_amdgcn_mfma_f32_16x16x32_bf16(kf0, aq[0][0], zero4, 0, 0, 0);
        c0[kt] = __builtin_amdgcn_mfma_f32_16x16x32_bf16(kf1, aq[0][1], tt, 0, 0, 0);
      }
      f32x4 tt1 = __builtin_amdgcn_mfma_f32_16x16x32_bf16(kf0, aq[1][0], zero4, 0, 0, 0);
      c1[kt] = __builtin_amdgcn_mfma_f32_16x16x32_bf16(kf1, aq[1][1], tt1, 0, 0, 0);
    }

    // --- softmax (no -mh2: constant cancels in o/l), packed P writes
    if (a0) SOFTMAX_P(c0, Pl[w][0], l0, qb0);
    SOFTMAX_P(c1, Pl[w][1], l1, qb1);

    // --- PV: A = P readback (row lr, contiguous keys), B = V^T frags
    bf16x8 vb[2][4];
#pragma unroll
    for (int c2 = 0; c2 < 2; ++c2)
#pragma unroll
      for (int nt = 0; nt < 4; ++nt)
        vb[c2][nt] = *(const bf16x8*)&Vs[bb][c2][(nt * 16 + lr) * 32 + quad * 8];
#pragma unroll
    for (int c2 = 0; c2 < 2; ++c2) {
      if (a0) {
        const bf16x8 pa0 = *(const bf16x8*)&Pl[w][0][lr * PLS + c2 * 32 + quad * 8];
#pragma unroll
        for (int nt = 0; nt < 4; ++nt)
          o[0][nt] = __builtin_amdgcn_mfma_f32_16x16x32_bf16(pa0, vb[c2][nt], o[0][nt], 0, 0, 0);
      }
      const bf16x8 pa1 = *(const bf16x8*)&Pl[w][1][lr * PLS + c2 * 32 + quad * 8];
#pragma unroll
      for (int nt = 0; nt < 4; ++nt)
        o[1][nt] = __builtin_amdgcn_mfma_f32_16x16x32_bf16(pa1, vb[c2][nt], o[1][nt], 0, 0, 0);
    }
  }
#undef SOFTMAX_P

  // --- epilogue: l lives per-lane for q=lr; reduce across quads, broadcast
  // the right row's 1/l to the C-layout rows (q=quad*4+r), write bf16.
#pragma unroll
  for (int qt = 0; qt < 2; ++qt) {
    float lt = qt ? l1 : l0;
    lt += __shfl_xor(lt, 16, 64);
    lt += __shfl_xor(lt, 32, 64);
    const float inv = 1.0f / lt;          // valid for q = lr
    const int qbt = qt ? qb1 : qb0;
#pragma unroll
    for (int r = 0; r < 4; ++r) {
      const float invr = __shfl(inv, quad * 4 + r, 16);  // 1/l for q=quad*4+r
      unsigned short* ar =
          attnb + ((size_t)(b * SEQ + qbt + quad * 4 + r)) * DMODEL + h * DHEAD;
#pragma unroll
      for (int nt = 0; nt < 4; ++nt) ar[nt * 16 + lr] = f2bf(o[qt][nt][r] * invr);
    }
  }
}

// ---------------------------------------------------------------------------
// Launch
// ---------------------------------------------------------------------------
extern "C" void kernel_launch(void* const* d_in, const int* in_sizes, int n_in,
                              void* d_out, int out_size, void* d_ws, size_t ws_size,
                              hipStream_t stream) {
  const float* x    = (const float*)d_in[0];
  // d_in[1]: fixed causal tril mask -> handled analytically, never read.
  const float* Wqkv = (const float*)d_in[2];
  const float* Wo   = (const float*)d_in[3];
  const float* tau  = (const float*)d_in[4];
  float* out = (float*)d_out;

  // workspace layout (~50 MB): no f32 qkv buffer anymore (norm fused in GEMM1)
  unsigned short* attnb = (unsigned short*)d_ws;                      // bf16 [B,S,D]
  unsigned short* Qh = attnb + (size_t)BATCH * SEQ * DMODEL;          // bf16 [B,H,S,DH]
  unsigned short* Kh = Qh + (size_t)BATCH * NHEAD * SEQ * DHEAD;
  unsigned short* Vh = Kh + (size_t)BATCH * NHEAD * SEQ * DHEAD;
  unsigned short* Xb = Vh + (size_t)BATCH * NHEAD * SEQ * DHEAD;      // bf16 [B*S][D]
  unsigned short* Wqkv_t = Xb + (size_t)BATCH * SEQ * DMODEL;         // bf16 [3D][D]
  unsigned short* Wo_t = Wqkv_t + (size_t)DMODEL * QKV_COLS;          // bf16 [D][D]
  unsigned short* Vt = Wo_t + (size_t)DMODEL * DMODEL;                // bf16 [BH][DH][S]

  const int M = BATCH * SEQ;  // 4096

  // 0) prep: bf16 conversions + weight transposes
  convert_x_kernel<<<(M * DMODEL) / (256 * 4), 256, 0, stream>>>(x, Xb);
  transpose_w_kernel<<<dim3(QKV_COLS / 32, DMODEL / 32), dim3(32, 8), 0, stream>>>(
      Wqkv, Wqkv_t, DMODEL, QKV_COLS);
  transpose_w_kernel<<<dim3(DMODEL / 32, DMODEL / 32), dim3(32, 8), 0, stream>>>(
      Wo, Wo_t, DMODEL, DMODEL);

  // 1) GEMM1 + fused qk-norm -> Qh/Kh/Vh bf16 head-major (no f32 round-trip)
  qkv_gemm_norm_kernel<<<dim3(QKV_COLS / 128, M / 128), 256, 0, stream>>>(
      Xb, Wqkv_t, tau, Qh, Kh, Vh);

  // 2) V -> V^T [BH][DH][S]
  vtrans_kernel<<<dim3(BATCH * NHEAD, SEQ / 64), 256, 0, stream>>>(Vh, Vt);

  // 3) causal MFMA flash attention -> attnb bf16 [B,S,D]
  attn_kernel<<<dim3(BATCH * NHEAD * SEQ / 128), 256, 0, stream>>>(
      Qh, Kh, Vt, attnb);

  // 4) out = attn @ Wo  (M=4096, N=1024, K=1024), f32 out
  sgemm_bf16_kernel<<<dim3(DMODEL / 128, M / 128), 256, 0, stream>>>(
      attnb, Wo_t, out, M, DMODEL, DMODEL);
}

// Round 9
// 210.536 us; speedup vs baseline: 1.6373x; 1.1135x over previous
//
#include <hip/hip_runtime.h>
#include <math.h>

// Problem constants (from reference): B=2, S=2048, D=1024, H=16, DH=64
#define BATCH 2
#define SEQ 2048
#define DMODEL 1024
#define NHEAD 16
#define DHEAD 64
#define QKV_COLS (3 * DMODEL)          // 3072
#define EPS 1e-8f
#define LOG2E 1.44269504f

typedef short bf16x8 __attribute__((ext_vector_type(8)));   // 8 bf16 (4 VGPRs)
typedef float f32x4 __attribute__((ext_vector_type(4)));    // 4 fp32 acc

// round-to-nearest-even float -> bf16 (as raw ushort)
static __device__ __forceinline__ unsigned short f2bf(float x) {
  unsigned u = __float_as_uint(x);
  u += 0x7fffu + ((u >> 16) & 1u);
  return (unsigned short)(u >> 16);
}

// pack two f32 -> (bf16(hi)<<16)|bf16(lo) in 3 VALU (round-half-up + v_perm)
static __device__ __forceinline__ unsigned pkbf(float lo, float hi) {
  const unsigned ul = __float_as_uint(lo) + 0x8000u;
  const unsigned uh = __float_as_uint(hi) + 0x8000u;
  return __builtin_amdgcn_perm(uh, ul, 0x07060302);  // [uh.hi16 | ul.hi16]
}

// async global->LDS, 16 B per lane (global_load_lds_dwordx4).
// LDS dest: wave-uniform base + lane*16 (m104/m108).
static __device__ __forceinline__ void async_ld16(const unsigned short* g,
                                                  unsigned short* l) {
  __builtin_amdgcn_global_load_lds(
      (const __attribute__((address_space(1))) void*)g,
      (__attribute__((address_space(3))) void*)(unsigned int)(unsigned long long)l,
      16, 0, 0);
}

// ---------------------------------------------------------------------------
// Prep 1: x f32 [M][K] -> bf16 same layout. 4 floats/thread.
// ---------------------------------------------------------------------------
__global__ __launch_bounds__(256) void convert_x_kernel(
    const float* __restrict__ x, unsigned short* __restrict__ xb) {
  const size_t i = ((size_t)blockIdx.x * 256 + threadIdx.x) * 4;
  const float4 a = *(const float4*)(x + i);
  ushort4 r;
  r.x = f2bf(a.x); r.y = f2bf(a.y); r.z = f2bf(a.z); r.w = f2bf(a.w);
  *(ushort4*)(xb + i) = r;
}

// ---------------------------------------------------------------------------
// Prep 2 (fused): both weight transposes in one launch.
// Region A: Wqkv [1024][3072] -> Wqkv_t [3072][1024] (96 col-tiles)
// Region B: Wo   [1024][1024] -> Wo_t   [1024][1024] (32 col-tiles)
// grid = (128, 32), block = (32, 8).
// ---------------------------------------------------------------------------
__global__ __launch_bounds__(256) void transpose_w2_kernel(
    const float* __restrict__ W0, unsigned short* __restrict__ Wt0,
    const float* __restrict__ W1, unsigned short* __restrict__ Wt1) {
  __shared__ float tile[32][33];
  const int bx = blockIdx.x;
  const float* W;
  unsigned short* Wt;
  int N, n0;
  if (bx < 96) { W = W0; Wt = Wt0; N = QKV_COLS; n0 = bx * 32; }
  else         { W = W1; Wt = Wt1; N = DMODEL;   n0 = (bx - 96) * 32; }
  const int K = DMODEL;
  const int k0 = blockIdx.y * 32;
  const int tx = threadIdx.x, ty = threadIdx.y;
#pragma unroll
  for (int i = 0; i < 4; ++i)
    tile[ty + i * 8][tx] = W[(size_t)(k0 + ty + i * 8) * N + n0 + tx];
  __syncthreads();
#pragma unroll
  for (int i = 0; i < 4; ++i)
    Wt[(size_t)(n0 + ty + i * 8) * K + k0 + tx] = f2bf(tile[tx][ty + i * 8]);
}

// ---------------------------------------------------------------------------
// bf16 MFMA GEMM, DOUBLE-BUFFERED staging (R9): one barrier/iter; loads for
// tile k+1 are issued right after the barrier and have the whole compute
// phase of tile k to land (R8's single-buffer exposed full load latency at
// every iteration's immediate vmcnt(0) drain).
// C[M,N] f32 = A[M,K]bf16 @ Bt[N,K]bf16^T. Used for GEMM2.
// ---------------------------------------------------------------------------
__global__ __launch_bounds__(256) void sgemm_bf16_kernel(
    const unsigned short* __restrict__ A, const unsigned short* __restrict__ Bt,
    float* __restrict__ C, int M, int N, int K) {
  __shared__ unsigned short As[2][128 * 32];   // [buf][m][k]
  __shared__ unsigned short Bs[2][128 * 32];   // [buf][n][k]

  const int t = threadIdx.x;
  const int w = t >> 6;
  const int lane = t & 63;
  const int quad = lane >> 4;
  const int lr = lane & 15;
  const int wr = w >> 1, wc = w & 1;
  const int m0 = blockIdx.y * 128;
  const int n0 = blockIdx.x * 128;

  const int srow = w * 32 + (lane >> 2);
  const int scol = (lane & 3) * 8;
  const unsigned short* ga = A + (size_t)(m0 + srow) * K + scol;
  const unsigned short* gb = Bt + (size_t)(n0 + srow) * K + scol;

  auto stage = [&](int k0, int bb) {
#pragma unroll
    for (int i = 0; i < 2; ++i) {
      async_ld16(ga + (size_t)(i * 16) * K + k0, &As[bb][(w * 32 + i * 16) * 32]);
      async_ld16(gb + (size_t)(i * 16) * K + k0, &Bs[bb][(w * 32 + i * 16) * 32]);
    }
  };

  f32x4 acc[4][4];
  const f32x4 zero4 = {0.f, 0.f, 0.f, 0.f};
#pragma unroll
  for (int i = 0; i < 4; ++i)
#pragma unroll
    for (int j = 0; j < 4; ++j) acc[i][j] = zero4;

  stage(0, 0);
  int bb = 0;
  for (int k0 = 0; k0 < K; k0 += 32, bb ^= 1) {
    __syncthreads();                        // buf bb ready; prior reads of bb^1 done
    if (k0 + 32 < K) stage(k0 + 32, bb ^ 1);

    bf16x8 af[4], bfr[4];
#pragma unroll
    for (int i = 0; i < 4; ++i)
      af[i] = *(const bf16x8*)&As[bb][(wr * 64 + i * 16 + lr) * 32 + quad * 8];
#pragma unroll
    for (int j = 0; j < 4; ++j)
      bfr[j] = *(const bf16x8*)&Bs[bb][(wc * 64 + j * 16 + lr) * 32 + quad * 8];
#pragma unroll
    for (int i = 0; i < 4; ++i)
#pragma unroll
      for (int j = 0; j < 4; ++j)
        acc[i][j] = __builtin_amdgcn_mfma_f32_16x16x32_bf16(af[i], bfr[j], acc[i][j], 0, 0, 0);
  }

#pragma unroll
  for (int i = 0; i < 4; ++i)
#pragma unroll
    for (int r = 0; r < 4; ++r) {
      float* c = C + (size_t)(m0 + wr * 64 + i * 16 + quad * 4 + r) * N + n0 + wc * 64 + lr;
#pragma unroll
      for (int j = 0; j < 4; ++j) c[j * 16] = acc[i][j][r];
    }
}

// ---------------------------------------------------------------------------
// GEMM1 + fused qk-norm, double-buffered (R9). Epilogue: per-row L2 norm of
// the wave's 64-col sub-tile (one (which,head) per wave), fold
// tau/sqrt(DH)*log2e into Q, write bf16 to Qh/Kh/Vh [B,H,S,DH].
// ---------------------------------------------------------------------------
__global__ __launch_bounds__(256) void qkv_gemm_norm_kernel(
    const unsigned short* __restrict__ A, const unsigned short* __restrict__ Bt,
    const float* __restrict__ tau,
    unsigned short* __restrict__ Qh, unsigned short* __restrict__ Kh,
    unsigned short* __restrict__ Vh) {
  __shared__ unsigned short As[2][128 * 32];
  __shared__ unsigned short Bs[2][128 * 32];

  const int K = DMODEL, N = QKV_COLS;
  const int t = threadIdx.x;
  const int w = t >> 6;
  const int lane = t & 63;
  const int quad = lane >> 4;
  const int lr = lane & 15;
  const int wr = w >> 1, wc = w & 1;
  const int m0 = blockIdx.y * 128;
  const int n0 = blockIdx.x * 128;

  const int srow = w * 32 + (lane >> 2);
  const int scol = (lane & 3) * 8;
  const unsigned short* ga = A + (size_t)(m0 + srow) * K + scol;
  const unsigned short* gb = Bt + (size_t)(n0 + srow) * K + scol;

  auto stage = [&](int k0, int bb) {
#pragma unroll
    for (int i = 0; i < 2; ++i) {
      async_ld16(ga + (size_t)(i * 16) * K + k0, &As[bb][(w * 32 + i * 16) * 32]);
      async_ld16(gb + (size_t)(i * 16) * K + k0, &Bs[bb][(w * 32 + i * 16) * 32]);
    }
  };

  f32x4 acc[4][4];
  const f32x4 zero4 = {0.f, 0.f, 0.f, 0.f};
#pragma unroll
  for (int i = 0; i < 4; ++i)
#pragma unroll
    for (int j = 0; j < 4; ++j) acc[i][j] = zero4;

  stage(0, 0);
  int bb = 0;
  for (int k0 = 0; k0 < K; k0 += 32, bb ^= 1) {
    __syncthreads();
    if (k0 + 32 < K) stage(k0 + 32, bb ^ 1);

    bf16x8 af[4], bfr[4];
#pragma unroll
    for (int i = 0; i < 4; ++i)
      af[i] = *(const bf16x8*)&As[bb][(wr * 64 + i * 16 + lr) * 32 + quad * 8];
#pragma unroll
    for (int j = 0; j < 4; ++j)
      bfr[j] = *(const bf16x8*)&Bs[bb][(wc * 64 + j * 16 + lr) * 32 + quad * 8];
#pragma unroll
    for (int i = 0; i < 4; ++i)
#pragma unroll
      for (int j = 0; j < 4; ++j)
        acc[i][j] = __builtin_amdgcn_mfma_f32_16x16x32_bf16(af[i], bfr[j], acc[i][j], 0, 0, 0);
  }

  // Epilogue: wave-uniform (which, head) from column block.
  const int col0 = n0 + wc * 64;
  const int which = col0 >> 10;             // 0=q, 1=k, 2=v
  const int h = (col0 & 1023) >> 6;
  const float tsc = tau[h] * 0.125f * LOG2E;
  unsigned short* dst = (which == 0) ? Qh : (which == 1) ? Kh : Vh;

#pragma unroll
  for (int i = 0; i < 4; ++i)
#pragma unroll
    for (int r = 0; r < 4; ++r) {
      const int s = m0 + wr * 64 + i * 16 + quad * 4 + r;   // global row 0..4095
      unsigned short* ar =
          dst + (((size_t)((s >> 11) * NHEAD + h)) * SEQ + (s & 2047)) * DHEAD;
      float scale;
      if (which == 2) {
        scale = 1.0f;
      } else {
        float ss = 0.f;
#pragma unroll
        for (int j = 0; j < 4; ++j) ss += acc[i][j][r] * acc[i][j][r];
        ss += __shfl_xor(ss, 1, 16);
        ss += __shfl_xor(ss, 2, 16);
        ss += __shfl_xor(ss, 4, 16);
        ss += __shfl_xor(ss, 8, 16);
        scale = 1.0f / (sqrtf(ss) + EPS);
        if (which == 0) scale *= tsc;       // tau/sqrt(DH) * log2e into Q
      }
#pragma unroll
      for (int j = 0; j < 4; ++j) ar[j * 16 + lr] = f2bf(acc[i][j][r] * scale);
    }
}

// ---------------------------------------------------------------------------
// V transpose: Vh [BH][S][DH] -> Vt [BH][DH][S]. 64x64 LDS tiles.
// ---------------------------------------------------------------------------
__global__ __launch_bounds__(256) void vtrans_kernel(
    const unsigned short* __restrict__ Vh, unsigned short* __restrict__ Vt) {
  __shared__ unsigned short tile[64][72];
  const int bh = blockIdx.x;
  const int s0 = blockIdx.y * 64;
  const int t = threadIdx.x;
  const int sr = t >> 2;          // 0..63
  const int dc = (t & 3) * 16;    // 0,16,32,48
  const unsigned short* src = Vh + ((size_t)bh * SEQ + s0 + sr) * DHEAD + dc;
  *(bf16x8*)&tile[sr][dc]     = *(const bf16x8*)(src);
  *(bf16x8*)&tile[sr][dc + 8] = *(const bf16x8*)(src + 8);
  __syncthreads();
  const int dr = t >> 2;          // 0..63 (d row)
  const int sc = (t & 3) * 16;    // s chunk
  unsigned short buf[16];
#pragma unroll
  for (int i = 0; i < 16; ++i) buf[i] = tile[sc + i][dr];
  unsigned short* dst = Vt + ((size_t)bh * DHEAD + dr) * SEQ + s0 + sc;
  *(bf16x8*)dst       = *(const bf16x8*)buf;
  *(bf16x8*)(dst + 8) = *(const bf16x8*)(buf + 8);
}

// ---------------------------------------------------------------------------
// Causal flash attention, bf16 MFMA, LDS-tiled K/V double-buffered, fixed-max
// exp2 softmax (no subtract), diagonal-only masking, packed P writes,
// balanced pairing (blocks c and 256+c sum to constant work). Unchanged
// from R8 (now below the GEMMs in the profile).
// ---------------------------------------------------------------------------
#define PLS 72   // P row stride in shorts (144 B)

__global__ __launch_bounds__(256, 2) void attn_kernel(
    const unsigned short* __restrict__ Qh, const unsigned short* __restrict__ Kh,
    const unsigned short* __restrict__ Vt, unsigned short* __restrict__ attnb) {
  __shared__ unsigned short Ks[2][2][64 * 32];   // [buf][d-half][key*32 + d']
  __shared__ unsigned short Vs[2][2][64 * 32];   // [buf][key-half][d*32 + key']
  __shared__ unsigned short Pl[4][2][16 * PLS];  // [wave][qt][q*PLS + key]

  const int idx = blockIdx.x;
  const int pair = idx >> 5;
  const int qblk = (idx < 256) ? (15 - pair) : (pair - 8);  // pairs sum to 17 steps
  const int bh = idx & 31;
  const int b = bh >> 4;
  const int h = bh & 15;
  const int t = threadIdx.x;
  const int w = t >> 6;
  const int lane = t & 63;
  const int quad = lane >> 4;
  const int lr = lane & 15;
  const int q0 = qblk * 128;
  const int kend = q0 + 128;

  const unsigned short* Qp = Qh + (size_t)bh * SEQ * DHEAD;
  const unsigned short* Kp = Kh + (size_t)bh * SEQ * DHEAD;
  const unsigned short* Vp = Vt + (size_t)bh * DHEAD * SEQ;

  const int srow = lane >> 2;        // 0..15 row within 16-row group
  const int scol = (lane & 3) * 8;   // shorts: 16B segment within 32-short row
  const int f0 = w * 4;

  auto stage = [&](int k0, int bb) {
#pragma unroll
    for (int i = 0; i < 4; ++i) {
      const int fi = f0 + i;
      if (fi < 8) {   // K half-tiles: [key][32 d'], rows 64B
        const int hh = fi >> 2, seg = fi & 3;
        async_ld16(Kp + (size_t)(k0 + seg * 16 + srow) * DHEAD + hh * 32 + scol,
                   &Ks[bb][hh][seg * 512]);
      } else {        // V^T half-tiles: [d][32 key'], rows 64B
        const int g = fi - 8;
        const int cc = g >> 2, seg = g & 3;
        async_ld16(Vp + (size_t)(seg * 16 + srow) * SEQ + k0 + cc * 32 + scol,
                   &Vs[bb][cc][seg * 512]);
      }
    }
  };

  const int qb0 = q0 + w * 16;        // q-tile 0 (dies on late steps)
  const int qb1 = q0 + 64 + w * 16;   // q-tile 1 (alive all steps)

  bf16x8 aq[2][2];
#pragma unroll
  for (int qt = 0; qt < 2; ++qt) {
    const unsigned short* qr = Qp + (size_t)((qt ? qb1 : qb0) + lr) * DHEAD;
    aq[qt][0] = *(const bf16x8*)(qr + quad * 8);
    aq[qt][1] = *(const bf16x8*)(qr + 32 + quad * 8);
  }

  const f32x4 zero4 = {0.f, 0.f, 0.f, 0.f};
  f32x4 o[2][4];
#pragma unroll
  for (int qt = 0; qt < 2; ++qt)
#pragma unroll
    for (int nt = 0; nt < 4; ++nt) o[qt][nt] = zero4;
  float l0 = 0.f, l1 = 0.f;

#define SOFTMAX_P(cArr, Pq, lAcc, qbt)                                       \
  do {                                                                       \
    float ps = 0.f;                                                          \
    if (k0 + 63 > (qbt)) {                                                   \
      const int qrow = (qbt) + lr;                                           \
      _Pragma("unroll")                                                      \
      for (int kt = 0; kt < 4; ++kt) {                                       \
        float p[4];                                                          \
        _Pragma("unroll")                                                    \
        for (int r = 0; r < 4; ++r) {                                        \
          const int key = k0 + kt * 16 + quad * 4 + r;                       \
          p[r] = (key <= qrow) ? exp2f(cArr[kt][r]) : 0.f;                   \
          ps += p[r];                                                        \
        }                                                                    \
        const unsigned lo = pkbf(p[0], p[1]);                                \
        const unsigned hi = pkbf(p[2], p[3]);                                \
        *(unsigned long long*)&(Pq)[lr * PLS + kt * 16 + quad * 4] =         \
            ((unsigned long long)hi << 32) | lo;                             \
      }                                                                      \
    } else {                                                                 \
      _Pragma("unroll")                                                      \
      for (int kt = 0; kt < 4; ++kt) {                                       \
        float p[4];                                                          \
        _Pragma("unroll")                                                    \
        for (int r = 0; r < 4; ++r) {                                        \
          p[r] = exp2f(cArr[kt][r]);                                         \
          ps += p[r];                                                        \
        }                                                                    \
        const unsigned lo = pkbf(p[0], p[1]);                                \
        const unsigned hi = pkbf(p[2], p[3]);                                \
        *(unsigned long long*)&(Pq)[lr * PLS + kt * 16 + quad * 4] =         \
            ((unsigned long long)hi << 32) | lo;                             \
      }                                                                      \
    }                                                                        \
    lAcc += ps;                                                              \
  } while (0)

  stage(0, 0);
  int bb = 0;
  for (int k0 = 0; k0 < kend; k0 += 64, bb ^= 1) {
    __syncthreads();                       // buf bb staged; prev reads done
    if (k0 + 64 < kend) stage(k0 + 64, bb ^ 1);

    const bool a0 = (k0 <= qb0 + 15);      // wave-uniform: q-tile 0 alive

    f32x4 c0[4], c1[4];
#pragma unroll
    for (int kt = 0; kt < 4; ++kt) {
      const bf16x8 kf0 = *(const bf16x8*)&Ks[bb][0][(kt * 16 + lr) * 32 + quad * 8];
      const bf16x8 kf1 = *(const bf16x8*)&Ks[bb][1][(kt * 16 + lr) * 32 + quad * 8];
      if (a0) {
        f32x4 tt = __builtin_amdgcn_mfma_f32_16x16x32_bf16(kf0, aq[0][0], zero4, 0, 0, 0);
        c0[kt] = __builtin_amdgcn_mfma_f32_16x16x32_bf16(kf1, aq[0][1], tt, 0, 0, 0);
      }
      f32x4 tt1 = __builtin_amdgcn_mfma_f32_16x16x32_bf16(kf0, aq[1][0], zero4, 0, 0, 0);
      c1[kt] = __builtin_amdgcn_mfma_f32_16x16x32_bf16(kf1, aq[1][1], tt1, 0, 0, 0);
    }

    if (a0) SOFTMAX_P(c0, Pl[w][0], l0, qb0);
    SOFTMAX_P(c1, Pl[w][1], l1, qb1);

    bf16x8 vb[2][4];
#pragma unroll
    for (int c2 = 0; c2 < 2; ++c2)
#pragma unroll
      for (int nt = 0; nt < 4; ++nt)
        vb[c2][nt] = *(const bf16x8*)&Vs[bb][c2][(nt * 16 + lr) * 32 + quad * 8];
#pragma unroll
    for (int c2 = 0; c2 < 2; ++c2) {
      if (a0) {
        const bf16x8 pa0 = *(const bf16x8*)&Pl[w][0][lr * PLS + c2 * 32 + quad * 8];
#pragma unroll
        for (int nt = 0; nt < 4; ++nt)
          o[0][nt] = __builtin_amdgcn_mfma_f32_16x16x32_bf16(pa0, vb[c2][nt], o[0][nt], 0, 0, 0);
      }
      const bf16x8 pa1 = *(const bf16x8*)&Pl[w][1][lr * PLS + c2 * 32 + quad * 8];
#pragma unroll
      for (int nt = 0; nt < 4; ++nt)
        o[1][nt] = __builtin_amdgcn_mfma_f32_16x16x32_bf16(pa1, vb[c2][nt], o[1][nt], 0, 0, 0);
    }
  }
#undef SOFTMAX_P

#pragma unroll
  for (int qt = 0; qt < 2; ++qt) {
    float lt = qt ? l1 : l0;
    lt += __shfl_xor(lt, 16, 64);
    lt += __shfl_xor(lt, 32, 64);
    const float inv = 1.0f / lt;          // valid for q = lr
    const int qbt = qt ? qb1 : qb0;
#pragma unroll
    for (int r = 0; r < 4; ++r) {
      const float invr = __shfl(inv, quad * 4 + r, 16);  // 1/l for q=quad*4+r
      unsigned short* ar =
          attnb + ((size_t)(b * SEQ + qbt + quad * 4 + r)) * DMODEL + h * DHEAD;
#pragma unroll
      for (int nt = 0; nt < 4; ++nt) ar[nt * 16 + lr] = f2bf(o[qt][nt][r] * invr);
    }
  }
}

// ---------------------------------------------------------------------------
// Launch
// ---------------------------------------------------------------------------
extern "C" void kernel_launch(void* const* d_in, const int* in_sizes, int n_in,
                              void* d_out, int out_size, void* d_ws, size_t ws_size,
                              hipStream_t stream) {
  const float* x    = (const float*)d_in[0];
  // d_in[1]: fixed causal tril mask -> handled analytically, never read.
  const float* Wqkv = (const float*)d_in[2];
  const float* Wo   = (const float*)d_in[3];
  const float* tau  = (const float*)d_in[4];
  float* out = (float*)d_out;

  // workspace layout (~50 MB): no f32 qkv buffer (norm fused in GEMM1)
  unsigned short* attnb = (unsigned short*)d_ws;                      // bf16 [B,S,D]
  unsigned short* Qh = attnb + (size_t)BATCH * SEQ * DMODEL;          // bf16 [B,H,S,DH]
  unsigned short* Kh = Qh + (size_t)BATCH * NHEAD * SEQ * DHEAD;
  unsigned short* Vh = Kh + (size_t)BATCH * NHEAD * SEQ * DHEAD;
  unsigned short* Xb = Vh + (size_t)BATCH * NHEAD * SEQ * DHEAD;      // bf16 [B*S][D]
  unsigned short* Wqkv_t = Xb + (size_t)BATCH * SEQ * DMODEL;         // bf16 [3D][D]
  unsigned short* Wo_t = Wqkv_t + (size_t)DMODEL * QKV_COLS;          // bf16 [D][D]
  unsigned short* Vt = Wo_t + (size_t)DMODEL * DMODEL;                // bf16 [BH][DH][S]

  const int M = BATCH * SEQ;  // 4096

  // 0) prep: bf16 conversion + fused weight transposes
  convert_x_kernel<<<(M * DMODEL) / (256 * 4), 256, 0, stream>>>(x, Xb);
  transpose_w2_kernel<<<dim3(128, 32), dim3(32, 8), 0, stream>>>(
      Wqkv, Wqkv_t, Wo, Wo_t);

  // 1) GEMM1 + fused qk-norm -> Qh/Kh/Vh bf16 head-major
  qkv_gemm_norm_kernel<<<dim3(QKV_COLS / 128, M / 128), 256, 0, stream>>>(
      Xb, Wqkv_t, tau, Qh, Kh, Vh);

  // 2) V -> V^T [BH][DH][S]
  vtrans_kernel<<<dim3(BATCH * NHEAD, SEQ / 64), 256, 0, stream>>>(Vh, Vt);

  // 3) causal MFMA flash attention -> attnb bf16 [B,S,D]
  attn_kernel<<<dim3(BATCH * NHEAD * SEQ / 128), 256, 0, stream>>>(
      Qh, Kh, Vt, attnb);

  // 4) out = attn @ Wo  (M=4096, N=1024, K=1024), f32 out
  sgemm_bf16_kernel<<<dim3(DMODEL / 128, M / 128), 256, 0, stream>>>(
      attnb, Wo_t, out, M, DMODEL, DMODEL);
}